// Round 2
// baseline (2885.870 us; speedup 1.0000x reference)
//
#include <hip/hip_runtime.h>
#include <math.h>

// Problem dims
// B=256, L=64, E=300, H=100, HID=200, V=30000, C=3
// Combined batch CB=512 (dir1 rows 0..255, dir2 rows 256..511)

__device__ __forceinline__ float sigf(float x) { return 1.f / (1.f + expf(-x)); }

// ---------------------------------------------------------------------------
// GEMM: out = A (MxK) * B^T (NxK)  or  A * B (KxN when TRANSB), + bias1+bias2
// GATHER: A row m -> emb[tok], tok from repA/repB with m = t*512 + b
// TRANSOUT: out[((m>>6)*N + n)*64 + (m&63)]  (used for WyY transposed store)
// ---------------------------------------------------------------------------
template<int GATHER, int TRANSB, int TRANSOUT>
__global__ void gemm_kernel(const float* __restrict__ A,
                            const int* __restrict__ repA, const int* __restrict__ repB,
                            const float* __restrict__ Bm,
                            const float* __restrict__ bias1, const float* __restrict__ bias2,
                            float* __restrict__ out, int M, int N, int K, int lda)
{
    __shared__ float As[8][132];
    __shared__ float Bs[8][132];
    int tid = threadIdx.x;
    int m0 = blockIdx.x * 128;
    int n0 = blockIdx.y * 128;
    int tx = tid & 15, ty = tid >> 4;
    float acc[8][8];
#pragma unroll
    for (int i = 0; i < 8; i++)
#pragma unroll
        for (int j = 0; j < 8; j++) acc[i][j] = 0.f;

    int mr = m0 + (tid >> 1);
    int p = tid & 1;
    const float* arow;
    if (GATHER) {
        int tt = mr >> 9;       // time
        int bb = mr & 511;      // combined batch
        int tok = (bb < 256) ? repA[bb * 64 + tt] : repB[(bb - 256) * 64 + tt];
        arow = A + (size_t)tok * lda;
    } else {
        arow = A + (size_t)mr * lda;
    }

    for (int k0 = 0; k0 < K; k0 += 8) {
        int kk = k0 + p * 4;
        float4 av = make_float4(0.f, 0.f, 0.f, 0.f);
        if (kk + 3 < K) {
            av = *(const float4*)(arow + kk);
        } else {
            float tmp[4] = {0.f, 0.f, 0.f, 0.f};
            for (int i = 0; i < 4; i++) if (kk + i < K) tmp[i] = arow[kk + i];
            av = make_float4(tmp[0], tmp[1], tmp[2], tmp[3]);
        }
        int ml = tid >> 1;
        As[p * 4 + 0][ml] = av.x; As[p * 4 + 1][ml] = av.y;
        As[p * 4 + 2][ml] = av.z; As[p * 4 + 3][ml] = av.w;

        if (!TRANSB) {
            int nl = tid >> 1;
            float4 bv = make_float4(0.f, 0.f, 0.f, 0.f);
            if (n0 + nl < N) {
                const float* brow = Bm + (size_t)(n0 + nl) * K;
                if (kk + 3 < K) {
                    bv = *(const float4*)(brow + kk);
                } else {
                    float tmp[4] = {0.f, 0.f, 0.f, 0.f};
                    for (int i = 0; i < 4; i++) if (kk + i < K) tmp[i] = brow[kk + i];
                    bv = make_float4(tmp[0], tmp[1], tmp[2], tmp[3]);
                }
            }
            Bs[p * 4 + 0][nl] = bv.x; Bs[p * 4 + 1][nl] = bv.y;
            Bs[p * 4 + 2][nl] = bv.z; Bs[p * 4 + 3][nl] = bv.w;
        } else {
            int kl = tid >> 5;
            int nc = (tid & 31) * 4;
            int krow = k0 + kl;
            float4 bv = make_float4(0.f, 0.f, 0.f, 0.f);
            if (krow < K) {
                if (n0 + nc + 3 < N) {
                    bv = *(const float4*)(Bm + (size_t)krow * N + n0 + nc);
                } else {
                    float tmp[4] = {0.f, 0.f, 0.f, 0.f};
                    for (int i = 0; i < 4; i++) if (n0 + nc + i < N) tmp[i] = Bm[(size_t)krow * N + n0 + nc + i];
                    bv = make_float4(tmp[0], tmp[1], tmp[2], tmp[3]);
                }
            }
            Bs[kl][nc + 0] = bv.x; Bs[kl][nc + 1] = bv.y;
            Bs[kl][nc + 2] = bv.z; Bs[kl][nc + 3] = bv.w;
        }
        __syncthreads();
#pragma unroll
        for (int k = 0; k < 8; k++) {
            float4 a0 = *(const float4*)&As[k][ty * 8];
            float4 a1 = *(const float4*)&As[k][ty * 8 + 4];
            float4 b0 = *(const float4*)&Bs[k][tx * 8];
            float4 b1 = *(const float4*)&Bs[k][tx * 8 + 4];
            float am[8] = {a0.x, a0.y, a0.z, a0.w, a1.x, a1.y, a1.z, a1.w};
            float bn[8] = {b0.x, b0.y, b0.z, b0.w, b1.x, b1.y, b1.z, b1.w};
#pragma unroll
            for (int i = 0; i < 8; i++)
#pragma unroll
                for (int j = 0; j < 8; j++) acc[i][j] += am[i] * bn[j];
        }
        __syncthreads();
    }

#pragma unroll
    for (int i = 0; i < 8; i++) {
        int m = m0 + ty * 8 + i;
#pragma unroll
        for (int j = 0; j < 8; j++) {
            int n = n0 + tx * 8 + j;
            if (n < N) {
                float v = acc[i][j];
                if (bias1) v += bias1[n] + bias2[n];
                size_t oi;
                if (TRANSOUT) oi = ((size_t)(m >> 6) * N + n) * 64 + (m & 63);
                else oi = (size_t)m * N + n;
                out[oi] = v;
            }
        }
    }
}

// ---------------------------------------------------------------------------
// Persistent LSTM over 64 steps. One block per 2 combined-batch rows.
// X: [64][512][400] precomputed x@Wih.T + b_ih + b_hh.
// W_hh rows cached in registers (100 VGPR / thread for threads < 400).
// phase1: hs_prev == nullptr -> zero init.
// phase2: init (h,c) from hs_prev/cs_prev at lenA-1 (lenA = b<256?len1:len2).
// ---------------------------------------------------------------------------
__global__ __launch_bounds__(512, 2)
void lstm_kernel(const float* __restrict__ X, const float* __restrict__ Whh,
                 const float* __restrict__ hs_prev, const float* __restrict__ cs_prev,
                 const int* __restrict__ len1, const int* __restrict__ len2,
                 float* __restrict__ hs_out, float* __restrict__ cs_out)
{
    int t = threadIdx.x;
    int b0 = blockIdx.x * 2, b1 = b0 + 1;
    __shared__ float4 h0s4[25], h1s4[25];
    __shared__ float g0s[400], g1s[400];
    float* h0s = (float*)h0s4;
    float* h1s = (float*)h1s4;

    float4 w[25];
    if (t < 400) {
        const float* wr = Whh + t * 100;
#pragma unroll
        for (int i = 0; i < 25; i++) w[i] = ((const float4*)wr)[i];
    }
    float c0r = 0.f, c1r = 0.f;
    if (hs_prev) {
        if (t < 100) {
            int la = (b0 < 256) ? len1[b0] : len2[b0 - 256];
            h0s[t] = hs_prev[(b0 * 64 + la - 1) * 100 + t];
            c0r = cs_prev[(b0 * 64 + la - 1) * 100 + t];
        } else if (t < 200) {
            int j = t - 100;
            int la = (b1 < 256) ? len1[b1] : len2[b1 - 256];
            h1s[j] = hs_prev[(b1 * 64 + la - 1) * 100 + j];
            c1r = cs_prev[(b1 * 64 + la - 1) * 100 + j];
        }
    } else {
        if (t < 100) h0s[t] = 0.f;
        else if (t < 200) h1s[t - 100] = 0.f;
    }
    __syncthreads();

    for (int ts = 0; ts < 64; ts++) {
        if (t < 400) {
            float acc0a = X[(ts * 512 + b0) * 400 + t];
            float acc1a = X[(ts * 512 + b1) * 400 + t];
            float acc0b = 0.f, acc1b = 0.f;
#pragma unroll
            for (int i = 0; i < 25; i++) {
                float4 hv0 = h0s4[i], hv1 = h1s4[i];
                acc0a += w[i].x * hv0.x + w[i].y * hv0.y;
                acc0b += w[i].z * hv0.z + w[i].w * hv0.w;
                acc1a += w[i].x * hv1.x + w[i].y * hv1.y;
                acc1b += w[i].z * hv1.z + w[i].w * hv1.w;
            }
            g0s[t] = acc0a + acc0b;
            g1s[t] = acc1a + acc1b;
        }
        __syncthreads();
        if (t < 200) {
            int j = (t < 100) ? t : t - 100;
            const float* gs = (t < 100) ? g0s : g1s;
            float ig = sigf(gs[j]);
            float fg = sigf(gs[100 + j]);
            float gg = tanhf(gs[200 + j]);
            float og = sigf(gs[300 + j]);
            float c = (t < 100) ? c0r : c1r;
            c = fg * c + ig * gg;
            float h = og * tanhf(c);
            if (t < 100) {
                c0r = c; h0s[j] = h;
                hs_out[(b0 * 64 + ts) * 100 + j] = h;
                if (cs_out) cs_out[(b0 * 64 + ts) * 100 + j] = c;
            } else {
                c1r = c; h1s[j] = h;
                hs_out[(b1 * 64 + ts) * 100 + j] = h;
                if (cs_out) cs_out[(b1 * 64 + ts) * 100 + j] = c;
            }
        }
        __syncthreads();
    }
}

// ---------------------------------------------------------------------------
// Persistent word-by-word attention. One block per 2 combined-batch rows.
// WyYT: [512][100][64] (transposed), outp = hs1 [512][64][100], hs2 same.
// Wh/Wr columns cached in registers (threads < 200).
// ---------------------------------------------------------------------------
__global__ __launch_bounds__(512, 2)
void attn_kernel(const float* __restrict__ WyYT, const float* __restrict__ outp,
                 const float* __restrict__ hs2,
                 const float* __restrict__ Wh, const float* __restrict__ Wr,
                 const float* __restrict__ Wp, const float* __restrict__ aW,
                 const float* __restrict__ mask1, const float* __restrict__ mask2,
                 const int* __restrict__ len1, const int* __restrict__ len2,
                 float* __restrict__ rep)
{
    int t = threadIdx.x;
    int b0 = blockIdx.x * 2, b1 = b0 + 1;
    __shared__ float4 ht4[2][25], cv4[2][25], wh4[2][25], a4[25], at4[2][16];
    __shared__ float4 cvsel4[2][25], lo4[2][25];
    __shared__ float spart[512];

    int jj = (t < 100) ? t : t - 100;  // output index for t<200 roles
    float whc[100], wrc[100];
    if (t < 200) {
#pragma unroll
        for (int k = 0; k < 100; k++) {
            whc[k] = Wh[k * 100 + jj];
            wrc[k] = Wr[k * 100 + jj];
        }
    }
    if (t < 25) a4[t] = ((const float4*)aW)[t];
    if (t < 200) ((float*)cv4)[t] = 0.f;

    // P3 roles: t = q*128 + (b*64 + l)
    int q = t >> 7, bl = t & 127, bq = bl >> 6, lq = bl & 63;
    int bgq = bq ? b1 : b0;
    float mreg3 = (bgq < 256) ? mask1[bgq * 64 + lq] : mask2[(bgq - 256) * 64 + lq];
    // P4 roles (t<128): b = t>>6, l = t&63
    int bp4 = t >> 6, lp4 = t & 63;
    float mreg = 0.f;
    if (t < 128) {
        int bg = bp4 ? b1 : b0;
        mreg = (bg < 256) ? mask1[bg * 64 + lp4] : mask2[(bg - 256) * 64 + lp4];
    }
    int lenB0 = (b0 < 256) ? len2[b0] : len1[b0 - 256];
    int lenB1 = (b1 < 256) ? len2[b1] : len1[b1 - 256];
    __syncthreads();

    for (int ts = 0; ts < 64; ts++) {
        // P1: stage h_t
        if (t < 200) {
            int bg = (t < 100) ? b0 : b1;
            ((float*)ht4)[t] = hs2[(bg * 64 + ts) * 100 + jj];
        }
        __syncthreads();
        // P2: WhH = h_t@Wh + cv@Wr  (register weight columns)
        if (t < 200) {
            int bh = (t < 100) ? 0 : 1;
            float acc = 0.f, acc2 = 0.f;
#pragma unroll
            for (int kk = 0; kk < 25; kk++) {
                float4 hv = ht4[bh][kk];
                float4 cvv = cv4[bh][kk];
                acc  += whc[4*kk] * hv.x + whc[4*kk+1] * hv.y + whc[4*kk+2] * hv.z + whc[4*kk+3] * hv.w;
                acc2 += wrc[4*kk] * cvv.x + wrc[4*kk+1] * cvv.y + wrc[4*kk+2] * cvv.z + wrc[4*kk+3] * cvv.w;
            }
            ((float*)wh4)[t] = acc + acc2;
        }
        __syncthreads();
        // P3: partial scores s[b][l] = sum_h a[h]*tanh(WyY + mask*WhH), h-split by q
        {
            float acc = 0.f;
            const float* wyp = WyYT + ((size_t)bgq * 100 + q * 25) * 64 + lq;
            const float* whp = ((const float*)wh4) + bq * 100 + q * 25;
            const float* ap = ((const float*)a4) + q * 25;
#pragma unroll
            for (int i = 0; i < 25; i++) {
                float x = wyp[i * 64] + mreg3 * whp[i];
                float e2 = __expf(2.f * x);
                float th = 1.f - 2.f / (e2 + 1.f);
                acc += ap[i] * th;
            }
            spart[t] = acc;
        }
        __syncthreads();
        // P4: reduce partials + masked softmax over l (wave per b)
        if (t < 128) {
            float s = spart[t] + spart[t + 128] + spart[t + 256] + spart[t + 384];
            float mx = s;
            for (int off = 32; off; off >>= 1) mx = fmaxf(mx, __shfl_xor(mx, off));
            float e = __expf(s - mx) * mreg;
            float sm = e;
            for (int off = 32; off; off >>= 1) sm += __shfl_xor(sm, off);
            ((float*)at4)[bp4 * 64 + lp4] = e / sm;
        }
        __syncthreads();
        // P5: cv_new[b][j] = sum_l attn[l]*outp[b][l][j]
        if (t < 200) {
            int bh = (t < 100) ? 0 : 1;
            int bg = bh ? b1 : b0;
            float acc = 0.f;
            const float* op = outp + (size_t)bg * 64 * 100 + jj;
#pragma unroll
            for (int ll = 0; ll < 16; ll++) {
                float4 av = at4[bh][ll];
                acc += av.x * op[(4*ll) * 100] + av.y * op[(4*ll+1) * 100]
                     + av.z * op[(4*ll+2) * 100] + av.w * op[(4*ll+3) * 100];
            }
            ((float*)cv4)[t] = acc;
            int lb = bh ? lenB1 : lenB0;
            if (ts == lb - 1) ((float*)cvsel4)[t] = acc;
        }
        __syncthreads();
    }

    // epilogue: rep = tanh(cv_sel @ Wp + lo @ Wh)
    if (t < 200) {
        int bh = (t < 100) ? 0 : 1;
        int bg = bh ? b1 : b0;
        int lb = bh ? lenB1 : lenB0;
        ((float*)lo4)[t] = hs2[(bg * 64 + lb - 1) * 100 + jj];
    }
    __syncthreads();
    if (t < 200) {
        int bh = (t < 100) ? 0 : 1;
        int bg = bh ? b1 : b0;
        const float* cvs = (const float*)&cvsel4[bh][0];
        const float* lo = (const float*)&lo4[bh][0];
        float acc = 0.f, acc2 = 0.f;
#pragma unroll
        for (int k = 0; k < 100; k++) {
            acc += cvs[k] * Wp[k * 100 + jj];
            acc2 += lo[k] * whc[k];
        }
        rep[bg * 100 + jj] = tanhf(acc + acc2);
    }
}

// ---------------------------------------------------------------------------
// Classifier: final=[f1|f2], fc=tanh(final@W1.T+b1), logits, log_softmax.
// One block per batch row b in [0,256).
// ---------------------------------------------------------------------------
__global__ void final_kernel(const float* __restrict__ rep,
                             const float* __restrict__ W1, const float* __restrict__ b1,
                             const float* __restrict__ W2, const float* __restrict__ b2,
                             float* __restrict__ out)
{
    int b = blockIdx.x;
    int t = threadIdx.x;
    __shared__ float4 fin4[50];
    __shared__ float4 fc4[50];
    __shared__ float lg[3];
    float* fin = (float*)fin4;
    float* fc = (float*)fc4;
    if (t < 200) fin[t] = (t < 100) ? rep[b * 100 + t] : rep[(b + 256) * 100 + (t - 100)];
    __syncthreads();
    if (t < 200) {
        float acc = b1[t];
        const float4* w = (const float4*)(W1 + t * 200);
#pragma unroll
        for (int k = 0; k < 50; k++) {
            float4 wv = w[k];
            float4 fv = fin4[k];
            acc += wv.x * fv.x + wv.y * fv.y + wv.z * fv.z + wv.w * fv.w;
        }
        fc[t] = tanhf(acc);
    }
    __syncthreads();
    if (t < 3) {
        float acc = b2[t];
        const float4* w = (const float4*)(W2 + t * 200);
        for (int k = 0; k < 50; k++) {
            float4 wv = w[k];
            float4 fv = fc4[k];
            acc += wv.x * fv.x + wv.y * fv.y + wv.z * fv.z + wv.w * fv.w;
        }
        lg[t] = acc;
    }
    __syncthreads();
    if (t == 0) {
        float m = fmaxf(lg[0], fmaxf(lg[1], lg[2]));
        float s = expf(lg[0] - m) + expf(lg[1] - m) + expf(lg[2] - m);
        float lse = m + logf(s);
        out[b * 3 + 0] = lg[0] - lse;
        out[b * 3 + 1] = lg[1] - lse;
        out[b * 3 + 2] = lg[2] - lse;
    }
}

// ---------------------------------------------------------------------------
extern "C" void kernel_launch(void* const* d_in, const int* in_sizes, int n_in,
                              void* d_out, int out_size, void* d_ws, size_t ws_size,
                              hipStream_t stream)
{
    const int*   rep1  = (const int*)d_in[0];
    const int*   len1  = (const int*)d_in[1];
    const float* mask1 = (const float*)d_in[2];
    const int*   rep2  = (const int*)d_in[3];
    const int*   len2  = (const int*)d_in[4];
    const float* mask2 = (const float*)d_in[5];
    const float* emb   = (const float*)d_in[6];
    const float* W_ih1 = (const float*)d_in[7];
    const float* W_hh1 = (const float*)d_in[8];
    const float* b_ih1 = (const float*)d_in[9];
    const float* b_hh1 = (const float*)d_in[10];
    const float* W_ih2 = (const float*)d_in[11];
    const float* W_hh2 = (const float*)d_in[12];
    const float* b_ih2 = (const float*)d_in[13];
    const float* b_hh2 = (const float*)d_in[14];
    const float* Wy    = (const float*)d_in[15];
    const float* Wh    = (const float*)d_in[16];
    const float* Wr    = (const float*)d_in[17];
    const float* Wp    = (const float*)d_in[18];
    const float* aW    = (const float*)d_in[19];
    const float* W1    = (const float*)d_in[20];
    const float* b1    = (const float*)d_in[21];
    const float* W2    = (const float*)d_in[22];
    const float* b2    = (const float*)d_in[23];

    float* ws = (float*)d_ws;
    float* X    = ws;                    // 64*512*400 = 13,107,200
    float* hs1  = X + 13107200;          // 512*64*100 = 3,276,800
    float* cs1  = hs1 + 3276800;
    float* hs2  = cs1 + 3276800;
    float* WyYT = hs2 + 3276800;
    float* rep  = WyYT + 3276800;        // 512*100 = 51,200
    // total ~105 MB

    dim3 gx(256, 4);   // M/128=256, ceil(400/128)=4
    dim3 gw(256, 1);   // ceil(100/128)=1

    // Xa = gather(emb via rep1|rep2) @ W_ih1.T + b_ih1 + b_hh1
    gemm_kernel<1, 0, 0><<<gx, 256, 0, stream>>>(emb, rep1, rep2, W_ih1, b_ih1, b_hh1,
                                                 X, 32768, 400, 300, 300);
    // LSTM1 (zero init), writes hs1, cs1
    lstm_kernel<<<256, 512, 0, stream>>>(X, W_hh1, nullptr, nullptr, nullptr, nullptr, hs1, cs1);
    // WyYT = (hs1 @ Wy) transposed-per-row-block
    gemm_kernel<0, 1, 1><<<gw, 256, 0, stream>>>(hs1, nullptr, nullptr, Wy, nullptr, nullptr,
                                                 WyYT, 32768, 100, 100, 100);
    // Xb = gather(emb via rep2|rep1) @ W_ih2.T + b_ih2 + b_hh2 (reuse X)
    gemm_kernel<1, 0, 0><<<gx, 256, 0, stream>>>(emb, rep2, rep1, W_ih2, b_ih2, b_hh2,
                                                 X, 32768, 400, 300, 300);
    // LSTM2, init from (hs1, cs1) at lenA-1, writes hs2
    lstm_kernel<<<256, 512, 0, stream>>>(X, W_hh2, hs1, cs1, len1, len2, hs2, nullptr);
    // Attention scan -> rep[512][100]
    attn_kernel<<<256, 512, 0, stream>>>(WyYT, hs1, hs2, Wh, Wr, Wp, aW,
                                         mask1, mask2, len1, len2, rep);
    // Classifier
    final_kernel<<<256, 256, 0, stream>>>(rep, W1, b1, W2, b2, (float*)d_out);
}

// Round 7
// 1017.197 us; speedup vs baseline: 2.8371x; 2.8371x over previous
//
#include <hip/hip_runtime.h>
#include <math.h>

// Problem dims
// B=256, L=64, E=300, H=100, HID=200, V=30000, C=3
// Combined batch CB=512 (dir1 rows 0..255, dir2 rows 256..511)

__device__ __forceinline__ float sigf(float x) { return 1.f / (1.f + expf(-x)); }

// ---------------------------------------------------------------------------
// GEMM: out = A (MxK) * B^T (NxK)  or  A * B (KxN when TRANSB), + bias1+bias2
// GATHER: A row m -> emb[tok], tok from repA/repB with m = t*512 + b
// TRANSOUT: out[((m>>6)*N + n)*64 + (m&63)]  (used for WyY transposed store)
// ---------------------------------------------------------------------------
template<int GATHER, int TRANSB, int TRANSOUT>
__global__ void gemm_kernel(const float* __restrict__ A,
                            const int* __restrict__ repA, const int* __restrict__ repB,
                            const float* __restrict__ Bm,
                            const float* __restrict__ bias1, const float* __restrict__ bias2,
                            float* __restrict__ out, int M, int N, int K, int lda)
{
    __shared__ float As[8][132];
    __shared__ float Bs[8][132];
    int tid = threadIdx.x;
    int m0 = blockIdx.x * 128;
    int n0 = blockIdx.y * 128;
    int tx = tid & 15, ty = tid >> 4;
    float acc[8][8];
#pragma unroll
    for (int i = 0; i < 8; i++)
#pragma unroll
        for (int j = 0; j < 8; j++) acc[i][j] = 0.f;

    int mr = m0 + (tid >> 1);
    int p = tid & 1;
    const float* arow;
    if (GATHER) {
        int tt = mr >> 9;       // time
        int bb = mr & 511;      // combined batch
        int tok = (bb < 256) ? repA[bb * 64 + tt] : repB[(bb - 256) * 64 + tt];
        arow = A + (size_t)tok * lda;
    } else {
        arow = A + (size_t)mr * lda;
    }

    for (int k0 = 0; k0 < K; k0 += 8) {
        int kk = k0 + p * 4;
        float4 av = make_float4(0.f, 0.f, 0.f, 0.f);
        if (kk + 3 < K) {
            av = *(const float4*)(arow + kk);
        } else {
            float tmp[4] = {0.f, 0.f, 0.f, 0.f};
            for (int i = 0; i < 4; i++) if (kk + i < K) tmp[i] = arow[kk + i];
            av = make_float4(tmp[0], tmp[1], tmp[2], tmp[3]);
        }
        int ml = tid >> 1;
        As[p * 4 + 0][ml] = av.x; As[p * 4 + 1][ml] = av.y;
        As[p * 4 + 2][ml] = av.z; As[p * 4 + 3][ml] = av.w;

        if (!TRANSB) {
            int nl = tid >> 1;
            float4 bv = make_float4(0.f, 0.f, 0.f, 0.f);
            if (n0 + nl < N) {
                const float* brow = Bm + (size_t)(n0 + nl) * K;
                if (kk + 3 < K) {
                    bv = *(const float4*)(brow + kk);
                } else {
                    float tmp[4] = {0.f, 0.f, 0.f, 0.f};
                    for (int i = 0; i < 4; i++) if (kk + i < K) tmp[i] = brow[kk + i];
                    bv = make_float4(tmp[0], tmp[1], tmp[2], tmp[3]);
                }
            }
            Bs[p * 4 + 0][nl] = bv.x; Bs[p * 4 + 1][nl] = bv.y;
            Bs[p * 4 + 2][nl] = bv.z; Bs[p * 4 + 3][nl] = bv.w;
        } else {
            int kl = tid >> 5;
            int nc = (tid & 31) * 4;
            int krow = k0 + kl;
            float4 bv = make_float4(0.f, 0.f, 0.f, 0.f);
            if (krow < K) {
                if (n0 + nc + 3 < N) {
                    bv = *(const float4*)(Bm + (size_t)krow * N + n0 + nc);
                } else {
                    float tmp[4] = {0.f, 0.f, 0.f, 0.f};
                    for (int i = 0; i < 4; i++) if (n0 + nc + i < N) tmp[i] = Bm[(size_t)krow * N + n0 + nc + i];
                    bv = make_float4(tmp[0], tmp[1], tmp[2], tmp[3]);
                }
            }
            Bs[kl][nc + 0] = bv.x; Bs[kl][nc + 1] = bv.y;
            Bs[kl][nc + 2] = bv.z; Bs[kl][nc + 3] = bv.w;
        }
        __syncthreads();
#pragma unroll
        for (int k = 0; k < 8; k++) {
            float4 a0 = *(const float4*)&As[k][ty * 8];
            float4 a1 = *(const float4*)&As[k][ty * 8 + 4];
            float4 b0 = *(const float4*)&Bs[k][tx * 8];
            float4 b1 = *(const float4*)&Bs[k][tx * 8 + 4];
            float am[8] = {a0.x, a0.y, a0.z, a0.w, a1.x, a1.y, a1.z, a1.w};
            float bn[8] = {b0.x, b0.y, b0.z, b0.w, b1.x, b1.y, b1.z, b1.w};
#pragma unroll
            for (int i = 0; i < 8; i++)
#pragma unroll
                for (int j = 0; j < 8; j++) acc[i][j] += am[i] * bn[j];
        }
        __syncthreads();
    }

#pragma unroll
    for (int i = 0; i < 8; i++) {
        int m = m0 + ty * 8 + i;
#pragma unroll
        for (int j = 0; j < 8; j++) {
            int n = n0 + tx * 8 + j;
            if (n < N) {
                float v = acc[i][j];
                if (bias1) v += bias1[n] + bias2[n];
                size_t oi;
                if (TRANSOUT) oi = ((size_t)(m >> 6) * N + n) * 64 + (m & 63);
                else oi = (size_t)m * N + n;
                out[oi] = v;
            }
        }
    }
}

// ---------------------------------------------------------------------------
// Persistent LSTM over 64 steps. One block per 2 combined-batch rows.
// X: [64][512][400] precomputed x@Wih.T + b_ih + b_hh.
// ---------------------------------------------------------------------------
__global__ __launch_bounds__(512, 2)
void lstm_kernel(const float* __restrict__ X, const float* __restrict__ Whh,
                 const float* __restrict__ hs_prev, const float* __restrict__ cs_prev,
                 const int* __restrict__ len1, const int* __restrict__ len2,
                 float* __restrict__ hs_out, float* __restrict__ cs_out)
{
    int t = threadIdx.x;
    int b0 = blockIdx.x * 2, b1 = b0 + 1;
    __shared__ float4 h0s4[25], h1s4[25];
    __shared__ float g0s[400], g1s[400];
    float* h0s = (float*)h0s4;
    float* h1s = (float*)h1s4;

    float4 w[25];
    if (t < 400) {
        const float* wr = Whh + t * 100;
#pragma unroll
        for (int i = 0; i < 25; i++) w[i] = ((const float4*)wr)[i];
    }
    float c0r = 0.f, c1r = 0.f;
    if (hs_prev) {
        if (t < 100) {
            int la = (b0 < 256) ? len1[b0] : len2[b0 - 256];
            h0s[t] = hs_prev[(b0 * 64 + la - 1) * 100 + t];
            c0r = cs_prev[(b0 * 64 + la - 1) * 100 + t];
        } else if (t < 200) {
            int j = t - 100;
            int la = (b1 < 256) ? len1[b1] : len2[b1 - 256];
            h1s[j] = hs_prev[(b1 * 64 + la - 1) * 100 + j];
            c1r = cs_prev[(b1 * 64 + la - 1) * 100 + j];
        }
    } else {
        if (t < 100) h0s[t] = 0.f;
        else if (t < 200) h1s[t - 100] = 0.f;
    }
    __syncthreads();

    for (int ts = 0; ts < 64; ts++) {
        if (t < 400) {
            // issue X loads first so the FMA chain hides their latency
            float x0 = X[(ts * 512 + b0) * 400 + t];
            float x1 = X[(ts * 512 + b1) * 400 + t];
            float acc0a = 0.f, acc1a = 0.f;
            float acc0b = 0.f, acc1b = 0.f;
#pragma unroll
            for (int i = 0; i < 25; i++) {
                float4 hv0 = h0s4[i], hv1 = h1s4[i];
                acc0a += w[i].x * hv0.x + w[i].y * hv0.y;
                acc0b += w[i].z * hv0.z + w[i].w * hv0.w;
                acc1a += w[i].x * hv1.x + w[i].y * hv1.y;
                acc1b += w[i].z * hv1.z + w[i].w * hv1.w;
            }
            g0s[t] = acc0a + acc0b + x0;
            g1s[t] = acc1a + acc1b + x1;
        }
        __syncthreads();
        if (t < 200) {
            int j = (t < 100) ? t : t - 100;
            const float* gs = (t < 100) ? g0s : g1s;
            float ig = sigf(gs[j]);
            float fg = sigf(gs[100 + j]);
            float gg = tanhf(gs[200 + j]);
            float og = sigf(gs[300 + j]);
            float c = (t < 100) ? c0r : c1r;
            c = fg * c + ig * gg;
            float h = og * tanhf(c);
            if (t < 100) {
                c0r = c; h0s[j] = h;
                hs_out[(b0 * 64 + ts) * 100 + j] = h;
                if (cs_out) cs_out[(b0 * 64 + ts) * 100 + j] = c;
            } else {
                c1r = c; h1s[j] = h;
                hs_out[(b1 * 64 + ts) * 100 + j] = h;
                if (cs_out) cs_out[(b1 * 64 + ts) * 100 + j] = c;
            }
        }
        __syncthreads();
    }
}

// ---------------------------------------------------------------------------
// Word-by-word attention, one batch row per block (512 blocks x 256 threads).
// WyYT [512][100][64] and outp [512][64][100] are staged in LDS ONCE.
// WhH_pre [512][64][100] = hs2 @ Wh precomputed by GEMM; only cv@Wr recurs.
// Per step: P2 cvWr -> P3 scores -> P4 softmax -> P5 cv update. 4 barriers.
// LDS ~54 KB -> 2 blocks/CU.
// ---------------------------------------------------------------------------
__global__ __launch_bounds__(256, 2)
void attn_kernel(const float* __restrict__ WyYT, const float* __restrict__ outp,
                 const float* __restrict__ WhH_pre,
                 const float* __restrict__ Wr, const float* __restrict__ Wp,
                 const float* __restrict__ aW,
                 const float* __restrict__ mask1, const float* __restrict__ mask2,
                 const int* __restrict__ len1, const int* __restrict__ len2,
                 float* __restrict__ rep)
{
    int t = threadIdx.x;
    int bg = blockIdx.x;            // 0..511 combined batch row
    __shared__ float wyy[100][64];  // 25.6 KB  [h][l]
    __shared__ float op[64][100];   // 25.6 KB  [l][h]
    __shared__ float4 cv4[25];      // context vector
    __shared__ float whq[100];      // WhH_pre[t] + cv@Wr
    __shared__ float spart[256];    // score partials
    __shared__ float4 at4[16];      // attention weights
    __shared__ float cvsel[100];
    __shared__ float avec[100];
    float* cv = (float*)cv4;

    // one-shot staging of WyY and outp rows for this batch element
    {
        const float4* wsrc = (const float4*)(WyYT + (size_t)bg * 6400);
        const float4* osrc = (const float4*)(outp + (size_t)bg * 6400);
        float4* wdst = (float4*)&wyy[0][0];
        float4* odst = (float4*)&op[0][0];
        for (int i = t; i < 1600; i += 256) {
            wdst[i] = wsrc[i];
            odst[i] = osrc[i];
        }
    }
    if (t < 100) { cv[t] = 0.f; avec[t] = aW[t]; }

    // Wr columns cached in registers (threads < 100): wrc4[i] holds Wr[4i..4i+3][jj]
    float4 wrc4[25];
    if (t < 100) {
#pragma unroll
        for (int i = 0; i < 25; i++)
            wrc4[i] = make_float4(Wr[(4 * i + 0) * 100 + t], Wr[(4 * i + 1) * 100 + t],
                                  Wr[(4 * i + 2) * 100 + t], Wr[(4 * i + 3) * 100 + t]);
    }

    int l = t & 63;
    float mreg = (bg < 256) ? mask1[bg * 64 + l] : mask2[(bg - 256) * 64 + l];
    int lenB = (bg < 256) ? len2[bg] : len1[bg - 256];
    int q = t >> 6;                 // h-quarter for P3

    float whn = (t < 100) ? WhH_pre[((size_t)bg * 64 + 0) * 100 + t] : 0.f;
    __syncthreads();

    for (int ts = 0; ts < 64; ts++) {
        // P2: whq = WhH_pre[ts] + cv @ Wr
        if (t < 100) {
            float acc = whn;
#pragma unroll
            for (int i = 0; i < 25; i++) {
                float4 c = cv4[i];
                acc += wrc4[i].x * c.x + wrc4[i].y * c.y + wrc4[i].z * c.z + wrc4[i].w * c.w;
            }
            whq[t] = acc;
        }
        __syncthreads();
        // prefetch next step's WhH_pre row (used 3 barriers later)
        if (t < 100 && ts < 63) whn = WhH_pre[((size_t)bg * 64 + ts + 1) * 100 + t];
        // P3: partial scores, h split in quarters
        {
            float acc = 0.f;
            const float* ap = avec + q * 25;
            const float* wq = whq + q * 25;
#pragma unroll
            for (int i = 0; i < 25; i++) {
                float x = wyy[q * 25 + i][l] + mreg * wq[i];
                float e2 = __expf(2.f * x);
                float th = 1.f - 2.f / (e2 + 1.f);
                acc += ap[i] * th;
            }
            spart[t] = acc;
        }
        __syncthreads();
        // P4: reduce quarters + masked softmax over l (single wave)
        if (t < 64) {
            float s = spart[t] + spart[t + 64] + spart[t + 128] + spart[t + 192];
            float mx = s;
            for (int off = 32; off; off >>= 1) mx = fmaxf(mx, __shfl_xor(mx, off));
            float e = __expf(s - mx) * mreg;
            float sm = e;
            for (int off = 32; off; off >>= 1) sm += __shfl_xor(sm, off);
            ((float*)at4)[t] = e / sm;
        }
        __syncthreads();
        // P5: cv_new[j] = sum_l attn[l] * outp[l][j]
        if (t < 100) {
            float acc = 0.f;
#pragma unroll
            for (int ll = 0; ll < 16; ll++) {
                float4 av = at4[ll];
                acc += av.x * op[4 * ll + 0][t] + av.y * op[4 * ll + 1][t]
                     + av.z * op[4 * ll + 2][t] + av.w * op[4 * ll + 3][t];
            }
            cv[t] = acc;
            if (ts == lenB - 1) cvsel[t] = acc;
        }
        __syncthreads();
    }

    // epilogue: rep = tanh(cv_sel @ Wp + lo @ Wh);  lo@Wh == WhH_pre[lenB-1]
    if (t < 100) {
        float acc = WhH_pre[((size_t)bg * 64 + lenB - 1) * 100 + t];
#pragma unroll
        for (int k = 0; k < 100; k++) acc += cvsel[k] * Wp[k * 100 + t];
        rep[(size_t)bg * 100 + t] = tanhf(acc);
    }
}

// ---------------------------------------------------------------------------
// Classifier: final=[f1|f2], fc=tanh(final@W1.T+b1), logits, log_softmax.
// ---------------------------------------------------------------------------
__global__ void final_kernel(const float* __restrict__ rep,
                             const float* __restrict__ W1, const float* __restrict__ b1,
                             const float* __restrict__ W2, const float* __restrict__ b2,
                             float* __restrict__ out)
{
    int b = blockIdx.x;
    int t = threadIdx.x;
    __shared__ float4 fin4[50];
    __shared__ float4 fc4[50];
    __shared__ float lg[3];
    float* fin = (float*)fin4;
    float* fc = (float*)fc4;
    if (t < 200) fin[t] = (t < 100) ? rep[b * 100 + t] : rep[(b + 256) * 100 + (t - 100)];
    __syncthreads();
    if (t < 200) {
        float acc = b1[t];
        const float4* w = (const float4*)(W1 + t * 200);
#pragma unroll
        for (int k = 0; k < 50; k++) {
            float4 wv = w[k];
            float4 fv = fin4[k];
            acc += wv.x * fv.x + wv.y * fv.y + wv.z * fv.z + wv.w * fv.w;
        }
        fc[t] = tanhf(acc);
    }
    __syncthreads();
    if (t < 3) {
        float acc = b2[t];
        const float4* w = (const float4*)(W2 + t * 200);
        for (int k = 0; k < 50; k++) {
            float4 wv = w[k];
            float4 fv = fc4[k];
            acc += wv.x * fv.x + wv.y * fv.y + wv.z * fv.z + wv.w * fv.w;
        }
        lg[t] = acc;
    }
    __syncthreads();
    if (t == 0) {
        float m = fmaxf(lg[0], fmaxf(lg[1], lg[2]));
        float s = expf(lg[0] - m) + expf(lg[1] - m) + expf(lg[2] - m);
        float lse = m + logf(s);
        out[b * 3 + 0] = lg[0] - lse;
        out[b * 3 + 1] = lg[1] - lse;
        out[b * 3 + 2] = lg[2] - lse;
    }
}

// ---------------------------------------------------------------------------
extern "C" void kernel_launch(void* const* d_in, const int* in_sizes, int n_in,
                              void* d_out, int out_size, void* d_ws, size_t ws_size,
                              hipStream_t stream)
{
    const int*   rep1  = (const int*)d_in[0];
    const int*   len1  = (const int*)d_in[1];
    const float* mask1 = (const float*)d_in[2];
    const int*   rep2  = (const int*)d_in[3];
    const int*   len2  = (const int*)d_in[4];
    const float* mask2 = (const float*)d_in[5];
    const float* emb   = (const float*)d_in[6];
    const float* W_ih1 = (const float*)d_in[7];
    const float* W_hh1 = (const float*)d_in[8];
    const float* b_ih1 = (const float*)d_in[9];
    const float* b_hh1 = (const float*)d_in[10];
    const float* W_ih2 = (const float*)d_in[11];
    const float* W_hh2 = (const float*)d_in[12];
    const float* b_ih2 = (const float*)d_in[13];
    const float* b_hh2 = (const float*)d_in[14];
    const float* Wy    = (const float*)d_in[15];
    const float* Wh    = (const float*)d_in[16];
    const float* Wr    = (const float*)d_in[17];
    const float* Wp    = (const float*)d_in[18];
    const float* aW    = (const float*)d_in[19];
    const float* W1    = (const float*)d_in[20];
    const float* b1    = (const float*)d_in[21];
    const float* W2    = (const float*)d_in[22];
    const float* b2    = (const float*)d_in[23];

    float* ws = (float*)d_ws;
    float* X    = ws;                    // 64*512*400 = 13,107,200 (also reused as WhH_pre)
    float* hs1  = X + 13107200;          // 512*64*100 = 3,276,800
    float* cs1  = hs1 + 3276800;
    float* hs2  = cs1 + 3276800;
    float* WyYT = hs2 + 3276800;
    float* rep  = WyYT + 3276800;        // 512*100 = 51,200
    // total ~105 MB

    dim3 gx(256, 4);   // M/128=256, ceil(400/128)=4
    dim3 gw(256, 1);   // ceil(100/128)=1

    // Xa = gather(emb via rep1|rep2) @ W_ih1.T + b_ih1 + b_hh1
    gemm_kernel<1, 0, 0><<<gx, 256, 0, stream>>>(emb, rep1, rep2, W_ih1, b_ih1, b_hh1,
                                                 X, 32768, 400, 300, 300);
    // LSTM1 (zero init), writes hs1, cs1
    lstm_kernel<<<256, 512, 0, stream>>>(X, W_hh1, nullptr, nullptr, nullptr, nullptr, hs1, cs1);
    // WyYT = (hs1 @ Wy) stored transposed per batch row: [512][100][64]
    gemm_kernel<0, 1, 1><<<gw, 256, 0, stream>>>(hs1, nullptr, nullptr, Wy, nullptr, nullptr,
                                                 WyYT, 32768, 100, 100, 100);
    // Xb = gather(emb via rep2|rep1) @ W_ih2.T + b_ih2 + b_hh2 (reuse X)
    gemm_kernel<1, 0, 0><<<gx, 256, 0, stream>>>(emb, rep2, rep1, W_ih2, b_ih2, b_hh2,
                                                 X, 32768, 400, 300, 300);
    // LSTM2, init from (hs1, cs1) at lenA-1, writes hs2
    lstm_kernel<<<256, 512, 0, stream>>>(X, W_hh2, hs1, cs1, len1, len2, hs2, nullptr);
    // WhH_pre = hs2 @ Wh  [512][64][100], stored into X (dead after LSTM2)
    gemm_kernel<0, 1, 0><<<gw, 256, 0, stream>>>(hs2, nullptr, nullptr, Wh, nullptr, nullptr,
                                                 X, 32768, 100, 100, 100);
    // Attention scan -> rep[512][100]
    attn_kernel<<<512, 256, 0, stream>>>(WyYT, hs1, X, Wr, Wp, aW,
                                         mask1, mask2, len1, len2, rep);
    // Classifier
    final_kernel<<<256, 256, 0, stream>>>(rep, W1, b1, W2, b2, (float*)d_out);
}

// Round 8
// 888.049 us; speedup vs baseline: 3.2497x; 1.1454x over previous
//
#include <hip/hip_runtime.h>
#include <math.h>

// Problem dims: B=256, L=64, E=300, H=100, HID=200, V=30000, C=3
// Combined batch CB=512 (dir1 rows 0..255, dir2 rows 256..511)

__device__ __forceinline__ float sigf(float x) { return 1.f / (1.f + expf(-x)); }

__device__ __forceinline__ unsigned short f2b(float f) {
    unsigned int u = __float_as_uint(f);
    unsigned int r = (u + 0x7FFFu + ((u >> 16) & 1u)) >> 16;   // RNE
    return (unsigned short)r;
}

typedef __attribute__((ext_vector_type(8))) short short8v;
typedef __attribute__((ext_vector_type(4))) float float4v;

// ---------------------------------------------------------------------------
// fp32 -> bf16 bulk convert (for emb); n4 = count/4
// ---------------------------------------------------------------------------
__global__ void f32_to_bf16_kernel(const float* __restrict__ in,
                                   unsigned short* __restrict__ out, int n4)
{
    int i = blockIdx.x * blockDim.x + threadIdx.x;
    int stride = gridDim.x * blockDim.x;
    for (; i < n4; i += stride) {
        float4 v = ((const float4*)in)[i];
        ushort4 b;
        b.x = f2b(v.x); b.y = f2b(v.y); b.z = f2b(v.z); b.w = f2b(v.w);
        ((ushort4*)out)[i] = b;
    }
}

// ---------------------------------------------------------------------------
// MFMA bf16 gather-GEMM: out[m][n] = emb_bf16[tok(m)][:] . W[n][:] + b1[n]+b2[n]
// M=32768 (m = t*512 + b), N=400, K=300.  BM=128, BN=80, BK=32.
// Fragment-ordered LDS: slot s=(tile,lane) holds 8 bf16 (16B) read lane-linearly.
// A and B share the lane->k map (k = (l>>4)*8 + i)  => permutation-safe.
// C/D: col = lane&15, row = (lane>>4)*4 + reg   (HW-verified mapping).
// ---------------------------------------------------------------------------
__global__ __launch_bounds__(256)
void gemm_xproj_mfma(const unsigned short* __restrict__ embb,
                     const int* __restrict__ repA, const int* __restrict__ repB,
                     const float* __restrict__ W,
                     const float* __restrict__ bias1, const float* __restrict__ bias2,
                     float* __restrict__ out)
{
    __shared__ __align__(16) unsigned short Afr[512 * 8];  // 8 KB
    __shared__ __align__(16) unsigned short Bfr[320 * 8];  // 5 KB
    int tid = threadIdx.x;
    int m0 = blockIdx.x * 128;
    int n0 = blockIdx.y * 80;
    int lane = tid & 63, wave = tid >> 6;

    // A slots (2 per thread)
    int sA0 = tid * 2, sA1 = sA0 + 1;
    int lA0 = sA0 & 63, lA1 = sA1 & 63;
    int rA0 = m0 + (sA0 >> 6) * 16 + (lA0 & 15);
    int rA1 = m0 + (sA1 >> 6) * 16 + (lA1 & 15);
    int kgA0 = (lA0 >> 4) * 8, kgA1 = (lA1 >> 4) * 8;
    int tt0 = rA0 >> 9, bb0 = rA0 & 511;
    int tok0 = (bb0 < 256) ? repA[bb0 * 64 + tt0] : repB[(bb0 - 256) * 64 + tt0];
    int tt1 = rA1 >> 9, bb1 = rA1 & 511;
    int tok1 = (bb1 < 256) ? repA[bb1 * 64 + tt1] : repB[(bb1 - 256) * 64 + tt1];
    const unsigned short* pa0 = embb + (size_t)tok0 * 300 + kgA0;
    const unsigned short* pa1 = embb + (size_t)tok1 * 300 + kgA1;

    // B slots: tid, plus tid+256 for tid<64
    int sB0 = tid;
    int nB0 = n0 + (sB0 >> 6) * 16 + (sB0 & 15);
    int kgB0 = ((sB0 & 63) >> 4) * 8;
    const float* pb0 = W + (size_t)nB0 * 300 + kgB0;
    int nB1 = n0 + 64 + (tid & 15);
    int kgB1 = (tid >> 4) * 8;  // valid for tid<64
    const float* pb1 = W + (size_t)nB1 * 300 + kgB1;

    float4v acc[2][5];
#pragma unroll
    for (int i = 0; i < 2; i++)
#pragma unroll
        for (int j = 0; j < 5; j++) acc[i][j] = (float4v){0.f, 0.f, 0.f, 0.f};

    for (int k0 = 0; k0 < 300; k0 += 32) {
        {   // A slot 0
            unsigned short* d = &Afr[sA0 * 8];
            int kk = k0 + kgA0;
            if (kk + 8 <= 300) {
                *(ushort4*)d = *(const ushort4*)(pa0 + k0);
                *(ushort4*)(d + 4) = *(const ushort4*)(pa0 + k0 + 4);
            } else {
#pragma unroll
                for (int i = 0; i < 8; i++) d[i] = (kk + i < 300) ? pa0[k0 + i] : 0;
            }
        }
        {   // A slot 1
            unsigned short* d = &Afr[sA1 * 8];
            int kk = k0 + kgA1;
            if (kk + 8 <= 300) {
                *(ushort4*)d = *(const ushort4*)(pa1 + k0);
                *(ushort4*)(d + 4) = *(const ushort4*)(pa1 + k0 + 4);
            } else {
#pragma unroll
                for (int i = 0; i < 8; i++) d[i] = (kk + i < 300) ? pa1[k0 + i] : 0;
            }
        }
        {   // B slot 0
            unsigned short* d = &Bfr[sB0 * 8];
            int kk = k0 + kgB0;
            if (kk + 8 <= 300) {
                float4 lo = *(const float4*)(pb0 + k0);
                float4 hi = *(const float4*)(pb0 + k0 + 4);
                d[0] = f2b(lo.x); d[1] = f2b(lo.y); d[2] = f2b(lo.z); d[3] = f2b(lo.w);
                d[4] = f2b(hi.x); d[5] = f2b(hi.y); d[6] = f2b(hi.z); d[7] = f2b(hi.w);
            } else {
#pragma unroll
                for (int i = 0; i < 8; i++) d[i] = (kk + i < 300) ? f2b(pb0[k0 + i]) : 0;
            }
        }
        if (tid < 64) {   // B slot 1 (nt=4)
            unsigned short* d = &Bfr[(256 + tid) * 8];
            int kk = k0 + kgB1;
            if (kk + 8 <= 300) {
                float4 lo = *(const float4*)(pb1 + k0);
                float4 hi = *(const float4*)(pb1 + k0 + 4);
                d[0] = f2b(lo.x); d[1] = f2b(lo.y); d[2] = f2b(lo.z); d[3] = f2b(lo.w);
                d[4] = f2b(hi.x); d[5] = f2b(hi.y); d[6] = f2b(hi.z); d[7] = f2b(hi.w);
            } else {
#pragma unroll
                for (int i = 0; i < 8; i++) d[i] = (kk + i < 300) ? f2b(pb1[k0 + i]) : 0;
            }
        }
        __syncthreads();
        short8v a0 = ((const short8v*)Afr)[(wave * 2 + 0) * 64 + lane];
        short8v a1 = ((const short8v*)Afr)[(wave * 2 + 1) * 64 + lane];
#pragma unroll
        for (int nt = 0; nt < 5; nt++) {
            short8v b = ((const short8v*)Bfr)[nt * 64 + lane];
            acc[0][nt] = __builtin_amdgcn_mfma_f32_16x16x32_bf16(a0, b, acc[0][nt], 0, 0, 0);
            acc[1][nt] = __builtin_amdgcn_mfma_f32_16x16x32_bf16(a1, b, acc[1][nt], 0, 0, 0);
        }
        __syncthreads();
    }

    int rbase = (lane >> 4) * 4;
    int cbase = lane & 15;
#pragma unroll
    for (int mtl = 0; mtl < 2; mtl++) {
        int mt = wave * 2 + mtl;
#pragma unroll
        for (int nt = 0; nt < 5; nt++) {
            int col = n0 + nt * 16 + cbase;
            float bsum = bias1[col] + bias2[col];
#pragma unroll
            for (int r = 0; r < 4; r++) {
                int row = m0 + mt * 16 + rbase + r;
                out[(size_t)row * 400 + col] = acc[mtl][nt][r] + bsum;
            }
        }
    }
}

// ---------------------------------------------------------------------------
// fp32 GEMM (kept for WyYT / WhH_pre): out = A * B (KxN), optional TRANSOUT
// ---------------------------------------------------------------------------
template<int TRANSB, int TRANSOUT>
__global__ void gemm_kernel(const float* __restrict__ A,
                            const float* __restrict__ Bm,
                            float* __restrict__ out, int M, int N, int K, int lda)
{
    __shared__ float As[8][132];
    __shared__ float Bs[8][132];
    int tid = threadIdx.x;
    int m0 = blockIdx.x * 128;
    int n0 = blockIdx.y * 128;
    int tx = tid & 15, ty = tid >> 4;
    float acc[8][8];
#pragma unroll
    for (int i = 0; i < 8; i++)
#pragma unroll
        for (int j = 0; j < 8; j++) acc[i][j] = 0.f;

    int mr = m0 + (tid >> 1);
    int p = tid & 1;
    const float* arow = A + (size_t)mr * lda;

    for (int k0 = 0; k0 < K; k0 += 8) {
        int kk = k0 + p * 4;
        float4 av = make_float4(0.f, 0.f, 0.f, 0.f);
        if (kk + 3 < K) {
            av = *(const float4*)(arow + kk);
        } else {
            float tmp[4] = {0.f, 0.f, 0.f, 0.f};
            for (int i = 0; i < 4; i++) if (kk + i < K) tmp[i] = arow[kk + i];
            av = make_float4(tmp[0], tmp[1], tmp[2], tmp[3]);
        }
        int ml = tid >> 1;
        As[p * 4 + 0][ml] = av.x; As[p * 4 + 1][ml] = av.y;
        As[p * 4 + 2][ml] = av.z; As[p * 4 + 3][ml] = av.w;

        {
            int kl = tid >> 5;
            int nc = (tid & 31) * 4;
            int krow = k0 + kl;
            float4 bv = make_float4(0.f, 0.f, 0.f, 0.f);
            if (krow < K) {
                if (n0 + nc + 3 < N) {
                    bv = *(const float4*)(Bm + (size_t)krow * N + n0 + nc);
                } else {
                    float tmp[4] = {0.f, 0.f, 0.f, 0.f};
                    for (int i = 0; i < 4; i++) if (n0 + nc + i < N) tmp[i] = Bm[(size_t)krow * N + n0 + nc + i];
                    bv = make_float4(tmp[0], tmp[1], tmp[2], tmp[3]);
                }
            }
            Bs[kl][nc + 0] = bv.x; Bs[kl][nc + 1] = bv.y;
            Bs[kl][nc + 2] = bv.z; Bs[kl][nc + 3] = bv.w;
        }
        __syncthreads();
#pragma unroll
        for (int k = 0; k < 8; k++) {
            float4 a0 = *(const float4*)&As[k][ty * 8];
            float4 a1 = *(const float4*)&As[k][ty * 8 + 4];
            float4 b0 = *(const float4*)&Bs[k][tx * 8];
            float4 b1 = *(const float4*)&Bs[k][tx * 8 + 4];
            float am[8] = {a0.x, a0.y, a0.z, a0.w, a1.x, a1.y, a1.z, a1.w};
            float bn[8] = {b0.x, b0.y, b0.z, b0.w, b1.x, b1.y, b1.z, b1.w};
#pragma unroll
            for (int i = 0; i < 8; i++)
#pragma unroll
                for (int j = 0; j < 8; j++) acc[i][j] += am[i] * bn[j];
        }
        __syncthreads();
    }

#pragma unroll
    for (int i = 0; i < 8; i++) {
        int m = m0 + ty * 8 + i;
#pragma unroll
        for (int j = 0; j < 8; j++) {
            int n = n0 + tx * 8 + j;
            if (n < N) {
                size_t oi;
                if (TRANSOUT) oi = ((size_t)(m >> 6) * N + n) * 64 + (m & 63);
                else oi = (size_t)m * N + n;
                out[oi] = acc[i][j];
            }
        }
    }
}

// ---------------------------------------------------------------------------
// Persistent LSTM, 2 rows/block, unchanged.
// ---------------------------------------------------------------------------
__global__ __launch_bounds__(512, 2)
void lstm_kernel(const float* __restrict__ X, const float* __restrict__ Whh,
                 const float* __restrict__ hs_prev, const float* __restrict__ cs_prev,
                 const int* __restrict__ len1, const int* __restrict__ len2,
                 float* __restrict__ hs_out, float* __restrict__ cs_out)
{
    int t = threadIdx.x;
    int b0 = blockIdx.x * 2, b1 = b0 + 1;
    __shared__ float4 h0s4[25], h1s4[25];
    __shared__ float g0s[400], g1s[400];
    float* h0s = (float*)h0s4;
    float* h1s = (float*)h1s4;

    float4 w[25];
    if (t < 400) {
        const float* wr = Whh + t * 100;
#pragma unroll
        for (int i = 0; i < 25; i++) w[i] = ((const float4*)wr)[i];
    }
    float c0r = 0.f, c1r = 0.f;
    if (hs_prev) {
        if (t < 100) {
            int la = (b0 < 256) ? len1[b0] : len2[b0 - 256];
            h0s[t] = hs_prev[(b0 * 64 + la - 1) * 100 + t];
            c0r = cs_prev[(b0 * 64 + la - 1) * 100 + t];
        } else if (t < 200) {
            int j = t - 100;
            int la = (b1 < 256) ? len1[b1] : len2[b1 - 256];
            h1s[j] = hs_prev[(b1 * 64 + la - 1) * 100 + j];
            c1r = cs_prev[(b1 * 64 + la - 1) * 100 + j];
        }
    } else {
        if (t < 100) h0s[t] = 0.f;
        else if (t < 200) h1s[t - 100] = 0.f;
    }
    __syncthreads();

    for (int ts = 0; ts < 64; ts++) {
        if (t < 400) {
            float x0 = X[(ts * 512 + b0) * 400 + t];
            float x1 = X[(ts * 512 + b1) * 400 + t];
            float acc0a = 0.f, acc1a = 0.f;
            float acc0b = 0.f, acc1b = 0.f;
#pragma unroll
            for (int i = 0; i < 25; i++) {
                float4 hv0 = h0s4[i], hv1 = h1s4[i];
                acc0a += w[i].x * hv0.x + w[i].y * hv0.y;
                acc0b += w[i].z * hv0.z + w[i].w * hv0.w;
                acc1a += w[i].x * hv1.x + w[i].y * hv1.y;
                acc1b += w[i].z * hv1.z + w[i].w * hv1.w;
            }
            g0s[t] = acc0a + acc0b + x0;
            g1s[t] = acc1a + acc1b + x1;
        }
        __syncthreads();
        if (t < 200) {
            int j = (t < 100) ? t : t - 100;
            const float* gs = (t < 100) ? g0s : g1s;
            float ig = sigf(gs[j]);
            float fg = sigf(gs[100 + j]);
            float gg = tanhf(gs[200 + j]);
            float og = sigf(gs[300 + j]);
            float c = (t < 100) ? c0r : c1r;
            c = fg * c + ig * gg;
            float h = og * tanhf(c);
            if (t < 100) {
                c0r = c; h0s[j] = h;
                hs_out[(b0 * 64 + ts) * 100 + j] = h;
                if (cs_out) cs_out[(b0 * 64 + ts) * 100 + j] = c;
            } else {
                c1r = c; h1s[j] = h;
                hs_out[(b1 * 64 + ts) * 100 + j] = h;
                if (cs_out) cs_out[(b1 * 64 + ts) * 100 + j] = c;
            }
        }
        __syncthreads();
    }
}

// ---------------------------------------------------------------------------
// One-wave attention: 512 blocks x 64 threads, one batch row per wave.
// wyy [l][h] (pre-doubled) and opt [h][l] staged once; Wr cols in 200 VGPRs.
// Per step: P2 cv@Wr -> P3 scores (sumA - 2a/(e^{2x}+1)) -> P4 shuffle softmax
// (max-free: |s| <= sum|a| ~ 25, no overflow/underflow) -> P5 cv update.
// __syncthreads on a 1-wave block is ~free.
// ---------------------------------------------------------------------------
__global__ __launch_bounds__(64)
void attn_wave(const float* __restrict__ WyYT, const float* __restrict__ outp,
               const float* __restrict__ WhH, const float* __restrict__ Wr,
               const float* __restrict__ Wp, const float* __restrict__ aW,
               const float* __restrict__ mask1, const float* __restrict__ mask2,
               const int* __restrict__ len1, const int* __restrict__ len2,
               float* __restrict__ rep)
{
    int lane = threadIdx.x;
    int bg = blockIdx.x;
    __shared__ __align__(16) float wyy[64][100];   // [l][h], = 2*WyY
    __shared__ __align__(16) float opt[100][68];   // [h][l], pad 68
    __shared__ __align__(16) float whq[100];
    __shared__ __align__(16) float cvl[100];
    __shared__ __align__(16) float atl[64];
    __shared__ __align__(16) float a2l[100];       // 2*a
    __shared__ __align__(16) float csel[100];

    int j1 = lane;
    bool has2 = lane < 36;
    int j2 = has2 ? lane + 64 : lane;

    const float* wy = WyYT + (size_t)bg * 6400;
    for (int h = 0; h < 100; h++)
        wyy[lane][h] = 2.f * wy[h * 64 + lane];
    const float* ob = outp + (size_t)bg * 6400;
    for (int l = 0; l < 64; l++) {
        opt[j1][l] = ob[l * 100 + j1];
        if (has2) opt[j2][l] = ob[l * 100 + j2];
    }
    a2l[j1] = 2.f * aW[j1];
    if (has2) a2l[j2] = 2.f * aW[j2];
    cvl[j1] = 0.f;
    if (has2) cvl[j2] = 0.f;
    __syncthreads();

    float sumA = 0.f;
    {
        const float4* a4 = (const float4*)a2l;
#pragma unroll
        for (int i = 0; i < 25; i++) { float4 v = a4[i]; sumA += v.x + v.y + v.z + v.w; }
        sumA *= 0.5f;
    }
    float mreg = (bg < 256) ? mask1[bg * 64 + lane] : mask2[(bg - 256) * 64 + lane];
    int lenB = (bg < 256) ? len2[bg] : len1[bg - 256];

    float wr1[100], wr2[100];
#pragma unroll
    for (int k = 0; k < 100; k++) {
        wr1[k] = Wr[k * 100 + j1];
        wr2[k] = Wr[k * 100 + j2];
    }
    const float* whrow = WhH + (size_t)bg * 6400;
    float wh1 = whrow[j1], wh2 = whrow[j2];
    float sel1 = 0.f, sel2 = 0.f;

    for (int ts = 0; ts < 64; ts++) {
        // P2: whq = 2*(WhH[ts] + cv@Wr)
        float acc1 = wh1, acc2 = wh2;
        const float4* cv4 = (const float4*)cvl;
#pragma unroll
        for (int i = 0; i < 25; i++) {
            float4 c = cv4[i];
            acc1 += wr1[4*i]*c.x + wr1[4*i+1]*c.y + wr1[4*i+2]*c.z + wr1[4*i+3]*c.w;
            acc2 += wr2[4*i]*c.x + wr2[4*i+1]*c.y + wr2[4*i+2]*c.z + wr2[4*i+3]*c.w;
        }
        whq[j1] = 2.f * acc1;
        if (has2) whq[j2] = 2.f * acc2;
        if (ts < 63) { wh1 = whrow[(ts + 1) * 100 + j1]; wh2 = whrow[(ts + 1) * 100 + j2]; }
        __syncthreads();

        // P3: neg = sum_h 2a[h] / (exp(2x)+1);  s = sumA - neg = sum_h a*tanh(x)
        float neg = 0.f;
        const float4* wq4 = (const float4*)whq;
        const float4* a24 = (const float4*)a2l;
        const float4* wyr = (const float4*)(&wyy[lane][0]);
#pragma unroll
        for (int i = 0; i < 25; i++) {
            float4 wv = wyr[i], qv = wq4[i], av = a24[i];
            neg += av.x * __builtin_amdgcn_rcpf(__expf(wv.x + mreg * qv.x) + 1.f);
            neg += av.y * __builtin_amdgcn_rcpf(__expf(wv.y + mreg * qv.y) + 1.f);
            neg += av.z * __builtin_amdgcn_rcpf(__expf(wv.z + mreg * qv.z) + 1.f);
            neg += av.w * __builtin_amdgcn_rcpf(__expf(wv.w + mreg * qv.w) + 1.f);
        }
        // P4: max-free masked softmax across the wave
        float s = sumA - neg;
        float e = __expf(s) * mreg;
        float sm = e;
#pragma unroll
        for (int off = 32; off; off >>= 1) sm += __shfl_xor(sm, off);
        atl[lane] = e / sm;
        __syncthreads();

        // P5: cv[j] = sum_l attn[l] * outp[l][j]
        float c1 = 0.f, c2 = 0.f;
        const float4* ap = (const float4*)atl;
        const float4* o1 = (const float4*)(&opt[j1][0]);
        const float4* o2 = (const float4*)(&opt[j2][0]);
#pragma unroll
        for (int i = 0; i < 16; i++) {
            float4 a = ap[i], v1 = o1[i], v2 = o2[i];
            c1 += a.x*v1.x + a.y*v1.y + a.z*v1.z + a.w*v1.w;
            c2 += a.x*v2.x + a.y*v2.y + a.z*v2.z + a.w*v2.w;
        }
        cvl[j1] = c1;
        if (has2) cvl[j2] = c2;
        if (ts == lenB - 1) { sel1 = c1; sel2 = c2; }
        __syncthreads();
    }

    // epilogue: rep = tanh(cv_sel @ Wp + WhH[lenB-1])
    csel[j1] = sel1;
    if (has2) csel[j2] = sel2;
    __syncthreads();
    float r1 = whrow[(lenB - 1) * 100 + j1];
    float r2 = whrow[(lenB - 1) * 100 + j2];
    const float4* cs4 = (const float4*)csel;
    for (int i = 0; i < 25; i++) {
        float4 c = cs4[i];
        r1 += c.x*Wp[(4*i)*100+j1] + c.y*Wp[(4*i+1)*100+j1] + c.z*Wp[(4*i+2)*100+j1] + c.w*Wp[(4*i+3)*100+j1];
        r2 += c.x*Wp[(4*i)*100+j2] + c.y*Wp[(4*i+1)*100+j2] + c.z*Wp[(4*i+2)*100+j2] + c.w*Wp[(4*i+3)*100+j2];
    }
    rep[(size_t)bg * 100 + j1] = tanhf(r1);
    if (has2) rep[(size_t)bg * 100 + j2] = tanhf(r2);
}

// ---------------------------------------------------------------------------
// Classifier, unchanged.
// ---------------------------------------------------------------------------
__global__ void final_kernel(const float* __restrict__ rep,
                             const float* __restrict__ W1, const float* __restrict__ b1,
                             const float* __restrict__ W2, const float* __restrict__ b2,
                             float* __restrict__ out)
{
    int b = blockIdx.x;
    int t = threadIdx.x;
    __shared__ float4 fin4[50];
    __shared__ float4 fc4[50];
    __shared__ float lg[3];
    float* fin = (float*)fin4;
    float* fc = (float*)fc4;
    if (t < 200) fin[t] = (t < 100) ? rep[b * 100 + t] : rep[(b + 256) * 100 + (t - 100)];
    __syncthreads();
    if (t < 200) {
        float acc = b1[t];
        const float4* w = (const float4*)(W1 + t * 200);
#pragma unroll
        for (int k = 0; k < 50; k++) {
            float4 wv = w[k];
            float4 fv = fin4[k];
            acc += wv.x * fv.x + wv.y * fv.y + wv.z * fv.z + wv.w * fv.w;
        }
        fc[t] = tanhf(acc);
    }
    __syncthreads();
    if (t < 3) {
        float acc = b2[t];
        const float4* w = (const float4*)(W2 + t * 200);
        for (int k = 0; k < 50; k++) {
            float4 wv = w[k];
            float4 fv = fc4[k];
            acc += wv.x * fv.x + wv.y * fv.y + wv.z * fv.z + wv.w * fv.w;
        }
        lg[t] = acc;
    }
    __syncthreads();
    if (t == 0) {
        float m = fmaxf(lg[0], fmaxf(lg[1], lg[2]));
        float s = expf(lg[0] - m) + expf(lg[1] - m) + expf(lg[2] - m);
        float lse = m + logf(s);
        out[b * 3 + 0] = lg[0] - lse;
        out[b * 3 + 1] = lg[1] - lse;
        out[b * 3 + 2] = lg[2] - lse;
    }
}

// ---------------------------------------------------------------------------
extern "C" void kernel_launch(void* const* d_in, const int* in_sizes, int n_in,
                              void* d_out, int out_size, void* d_ws, size_t ws_size,
                              hipStream_t stream)
{
    const int*   rep1  = (const int*)d_in[0];
    const int*   len1  = (const int*)d_in[1];
    const float* mask1 = (const float*)d_in[2];
    const int*   rep2  = (const int*)d_in[3];
    const int*   len2  = (const int*)d_in[4];
    const float* mask2 = (const float*)d_in[5];
    const float* emb   = (const float*)d_in[6];
    const float* W_ih1 = (const float*)d_in[7];
    const float* W_hh1 = (const float*)d_in[8];
    const float* b_ih1 = (const float*)d_in[9];
    const float* b_hh1 = (const float*)d_in[10];
    const float* W_ih2 = (const float*)d_in[11];
    const float* W_hh2 = (const float*)d_in[12];
    const float* b_ih2 = (const float*)d_in[13];
    const float* b_hh2 = (const float*)d_in[14];
    const float* Wy    = (const float*)d_in[15];
    const float* Wh    = (const float*)d_in[16];
    const float* Wr    = (const float*)d_in[17];
    const float* Wp    = (const float*)d_in[18];
    const float* aW    = (const float*)d_in[19];
    const float* W1    = (const float*)d_in[20];
    const float* b1    = (const float*)d_in[21];
    const float* W2    = (const float*)d_in[22];
    const float* b2    = (const float*)d_in[23];

    float* ws = (float*)d_ws;
    float* X    = ws;                    // 64*512*400 = 13,107,200 (reused as WhH_pre)
    float* hs1  = X + 13107200;          // 512*64*100
    float* cs1  = hs1 + 3276800;
    float* hs2  = cs1 + 3276800;
    float* WyYT = hs2 + 3276800;
    float* rep  = WyYT + 3276800;        // 512*100
    // emb_bf16 overlay: lives in hs2 + head of WyYT (9,000,000 ushorts =
    // 4,500,000 float slots < hs2+WyYT = 6,553,600). Dead before lstm2/WyYT-gemm.
    unsigned short* embb = (unsigned short*)hs2;

    dim3 gm(256, 5);   // MFMA gather-GEMM: M/128=256, N/80=5
    dim3 gw(256, 1);   // fp32 GEMM N=100

    // 1. emb -> bf16
    f32_to_bf16_kernel<<<1024, 256, 0, stream>>>(emb, embb, 2250000);
    // 2. Xa = gather(emb_bf) @ W_ih1^T + b_ih1 + b_hh1   (MFMA)
    gemm_xproj_mfma<<<gm, 256, 0, stream>>>(embb, rep1, rep2, W_ih1, b_ih1, b_hh1, X);
    // 3. LSTM1 (zero init) -> hs1, cs1
    lstm_kernel<<<256, 512, 0, stream>>>(X, W_hh1, nullptr, nullptr, nullptr, nullptr, hs1, cs1);
    // 4. Xb = gather(emb_bf, swapped) @ W_ih2^T + biases  (MFMA, reuse X; embb last use)
    gemm_xproj_mfma<<<gm, 256, 0, stream>>>(embb, rep2, rep1, W_ih2, b_ih2, b_hh2, X);
    // 5. WyYT = (hs1 @ Wy) transposed per row [512][100][64]  (overwrites embb tail - dead)
    gemm_kernel<1, 1><<<gw, 256, 0, stream>>>(hs1, Wy, WyYT, 32768, 100, 100, 100);
    // 6. LSTM2 -> hs2 (overwrites embb head - dead)
    lstm_kernel<<<256, 512, 0, stream>>>(X, W_hh2, hs1, cs1, len1, len2, hs2, nullptr);
    // 7. WhH_pre = hs2 @ Wh -> X
    gemm_kernel<1, 0><<<gw, 256, 0, stream>>>(hs2, Wh, X, 32768, 100, 100, 100);
    // 8. attention scan -> rep
    attn_wave<<<512, 64, 0, stream>>>(WyYT, hs1, X, Wr, Wp, aW,
                                      mask1, mask2, len1, len2, rep);
    // 9. classifier
    final_kernel<<<256, 256, 0, stream>>>(rep, W1, b1, W2, b2, (float*)d_out);
}

// Round 9
// 717.853 us; speedup vs baseline: 4.0201x; 1.2371x over previous
//
#include <hip/hip_runtime.h>
#include <math.h>

// Problem dims: B=256, L=64, E=300, H=100, HID=200, V=30000, C=3
// Combined batch CB=512 (dir1 rows 0..255, dir2 rows 256..511)

__device__ __forceinline__ float sigf(float x) { return 1.f / (1.f + expf(-x)); }

__device__ __forceinline__ unsigned short f2b(float f) {
    unsigned int u = __float_as_uint(f);
    unsigned int r = (u + 0x7FFFu + ((u >> 16) & 1u)) >> 16;   // RNE
    return (unsigned short)r;
}

typedef __attribute__((ext_vector_type(8))) short short8v;
typedef __attribute__((ext_vector_type(4))) float float4v;

// ---------------------------------------------------------------------------
// fp32 -> bf16 bulk convert (for emb); n4 = count/4
// ---------------------------------------------------------------------------
__global__ void f32_to_bf16_kernel(const float* __restrict__ in,
                                   unsigned short* __restrict__ out, int n4)
{
    int i = blockIdx.x * blockDim.x + threadIdx.x;
    int stride = gridDim.x * blockDim.x;
    for (; i < n4; i += stride) {
        float4 v = ((const float4*)in)[i];
        ushort4 b;
        b.x = f2b(v.x); b.y = f2b(v.y); b.z = f2b(v.z); b.w = f2b(v.w);
        ((ushort4*)out)[i] = b;
    }
}

// ---------------------------------------------------------------------------
// MFMA bf16 gather-GEMM (unchanged from round 8, passed with absmax 7.8e-3).
// out[m][n] = emb_bf16[tok(m)][:] . W[n][:] + b1[n]+b2[n]
// M=32768 (m = t*512 + b), N=400, K=300.  BM=128, BN=80, BK=32.
// ---------------------------------------------------------------------------
__global__ __launch_bounds__(256)
void gemm_xproj_mfma(const unsigned short* __restrict__ embb,
                     const int* __restrict__ repA, const int* __restrict__ repB,
                     const float* __restrict__ W,
                     const float* __restrict__ bias1, const float* __restrict__ bias2,
                     float* __restrict__ out)
{
    __shared__ __align__(16) unsigned short Afr[512 * 8];  // 8 KB
    __shared__ __align__(16) unsigned short Bfr[320 * 8];  // 5 KB
    int tid = threadIdx.x;
    int m0 = blockIdx.x * 128;
    int n0 = blockIdx.y * 80;
    int lane = tid & 63, wave = tid >> 6;

    int sA0 = tid * 2, sA1 = sA0 + 1;
    int lA0 = sA0 & 63, lA1 = sA1 & 63;
    int rA0 = m0 + (sA0 >> 6) * 16 + (lA0 & 15);
    int rA1 = m0 + (sA1 >> 6) * 16 + (lA1 & 15);
    int kgA0 = (lA0 >> 4) * 8, kgA1 = (lA1 >> 4) * 8;
    int tt0 = rA0 >> 9, bb0 = rA0 & 511;
    int tok0 = (bb0 < 256) ? repA[bb0 * 64 + tt0] : repB[(bb0 - 256) * 64 + tt0];
    int tt1 = rA1 >> 9, bb1 = rA1 & 511;
    int tok1 = (bb1 < 256) ? repA[bb1 * 64 + tt1] : repB[(bb1 - 256) * 64 + tt1];
    const unsigned short* pa0 = embb + (size_t)tok0 * 300 + kgA0;
    const unsigned short* pa1 = embb + (size_t)tok1 * 300 + kgA1;

    int sB0 = tid;
    int nB0 = n0 + (sB0 >> 6) * 16 + (sB0 & 15);
    int kgB0 = ((sB0 & 63) >> 4) * 8;
    const float* pb0 = W + (size_t)nB0 * 300 + kgB0;
    int nB1 = n0 + 64 + (tid & 15);
    int kgB1 = (tid >> 4) * 8;
    const float* pb1 = W + (size_t)nB1 * 300 + kgB1;

    float4v acc[2][5];
#pragma unroll
    for (int i = 0; i < 2; i++)
#pragma unroll
        for (int j = 0; j < 5; j++) acc[i][j] = (float4v){0.f, 0.f, 0.f, 0.f};

    for (int k0 = 0; k0 < 300; k0 += 32) {
        {
            unsigned short* d = &Afr[sA0 * 8];
            int kk = k0 + kgA0;
            if (kk + 8 <= 300) {
                *(ushort4*)d = *(const ushort4*)(pa0 + k0);
                *(ushort4*)(d + 4) = *(const ushort4*)(pa0 + k0 + 4);
            } else {
#pragma unroll
                for (int i = 0; i < 8; i++) d[i] = (kk + i < 300) ? pa0[k0 + i] : 0;
            }
        }
        {
            unsigned short* d = &Afr[sA1 * 8];
            int kk = k0 + kgA1;
            if (kk + 8 <= 300) {
                *(ushort4*)d = *(const ushort4*)(pa1 + k0);
                *(ushort4*)(d + 4) = *(const ushort4*)(pa1 + k0 + 4);
            } else {
#pragma unroll
                for (int i = 0; i < 8; i++) d[i] = (kk + i < 300) ? pa1[k0 + i] : 0;
            }
        }
        {
            unsigned short* d = &Bfr[sB0 * 8];
            int kk = k0 + kgB0;
            if (kk + 8 <= 300) {
                float4 lo = *(const float4*)(pb0 + k0);
                float4 hi = *(const float4*)(pb0 + k0 + 4);
                d[0] = f2b(lo.x); d[1] = f2b(lo.y); d[2] = f2b(lo.z); d[3] = f2b(lo.w);
                d[4] = f2b(hi.x); d[5] = f2b(hi.y); d[6] = f2b(hi.z); d[7] = f2b(hi.w);
            } else {
#pragma unroll
                for (int i = 0; i < 8; i++) d[i] = (kk + i < 300) ? f2b(pb0[k0 + i]) : 0;
            }
        }
        if (tid < 64) {
            unsigned short* d = &Bfr[(256 + tid) * 8];
            int kk = k0 + kgB1;
            if (kk + 8 <= 300) {
                float4 lo = *(const float4*)(pb1 + k0);
                float4 hi = *(const float4*)(pb1 + k0 + 4);
                d[0] = f2b(lo.x); d[1] = f2b(lo.y); d[2] = f2b(lo.z); d[3] = f2b(lo.w);
                d[4] = f2b(hi.x); d[5] = f2b(hi.y); d[6] = f2b(hi.z); d[7] = f2b(hi.w);
            } else {
#pragma unroll
                for (int i = 0; i < 8; i++) d[i] = (kk + i < 300) ? f2b(pb1[k0 + i]) : 0;
            }
        }
        __syncthreads();
        short8v a0 = ((const short8v*)Afr)[(wave * 2 + 0) * 64 + lane];
        short8v a1 = ((const short8v*)Afr)[(wave * 2 + 1) * 64 + lane];
#pragma unroll
        for (int nt = 0; nt < 5; nt++) {
            short8v b = ((const short8v*)Bfr)[nt * 64 + lane];
            acc[0][nt] = __builtin_amdgcn_mfma_f32_16x16x32_bf16(a0, b, acc[0][nt], 0, 0, 0);
            acc[1][nt] = __builtin_amdgcn_mfma_f32_16x16x32_bf16(a1, b, acc[1][nt], 0, 0, 0);
        }
        __syncthreads();
    }

    int rbase = (lane >> 4) * 4;
    int cbase = lane & 15;
#pragma unroll
    for (int mtl = 0; mtl < 2; mtl++) {
        int mt = wave * 2 + mtl;
#pragma unroll
        for (int nt = 0; nt < 5; nt++) {
            int col = n0 + nt * 16 + cbase;
            float bsum = bias1[col] + bias2[col];
#pragma unroll
            for (int r = 0; r < 4; r++) {
                int row = m0 + mt * 16 + rbase + r;
                out[(size_t)row * 400 + col] = acc[mtl][nt][r] + bsum;
            }
        }
    }
}

// ---------------------------------------------------------------------------
// fp32 GEMM (WyYT / WhH_pre): out = A * B (KxN), optional TRANSOUT
// ---------------------------------------------------------------------------
template<int TRANSB, int TRANSOUT>
__global__ void gemm_kernel(const float* __restrict__ A,
                            const float* __restrict__ Bm,
                            float* __restrict__ out, int M, int N, int K, int lda)
{
    __shared__ float As[8][132];
    __shared__ float Bs[8][132];
    int tid = threadIdx.x;
    int m0 = blockIdx.x * 128;
    int n0 = blockIdx.y * 128;
    int tx = tid & 15, ty = tid >> 4;
    float acc[8][8];
#pragma unroll
    for (int i = 0; i < 8; i++)
#pragma unroll
        for (int j = 0; j < 8; j++) acc[i][j] = 0.f;

    int mr = m0 + (tid >> 1);
    int p = tid & 1;
    const float* arow = A + (size_t)mr * lda;

    for (int k0 = 0; k0 < K; k0 += 8) {
        int kk = k0 + p * 4;
        float4 av = make_float4(0.f, 0.f, 0.f, 0.f);
        if (kk + 3 < K) {
            av = *(const float4*)(arow + kk);
        } else {
            float tmp[4] = {0.f, 0.f, 0.f, 0.f};
            for (int i = 0; i < 4; i++) if (kk + i < K) tmp[i] = arow[kk + i];
            av = make_float4(tmp[0], tmp[1], tmp[2], tmp[3]);
        }
        int ml = tid >> 1;
        As[p * 4 + 0][ml] = av.x; As[p * 4 + 1][ml] = av.y;
        As[p * 4 + 2][ml] = av.z; As[p * 4 + 3][ml] = av.w;

        {
            int kl = tid >> 5;
            int nc = (tid & 31) * 4;
            int krow = k0 + kl;
            float4 bv = make_float4(0.f, 0.f, 0.f, 0.f);
            if (krow < K) {
                if (n0 + nc + 3 < N) {
                    bv = *(const float4*)(Bm + (size_t)krow * N + n0 + nc);
                } else {
                    float tmp[4] = {0.f, 0.f, 0.f, 0.f};
                    for (int i = 0; i < 4; i++) if (n0 + nc + i < N) tmp[i] = Bm[(size_t)krow * N + n0 + nc + i];
                    bv = make_float4(tmp[0], tmp[1], tmp[2], tmp[3]);
                }
            }
            Bs[kl][nc + 0] = bv.x; Bs[kl][nc + 1] = bv.y;
            Bs[kl][nc + 2] = bv.z; Bs[kl][nc + 3] = bv.w;
        }
        __syncthreads();
#pragma unroll
        for (int k = 0; k < 8; k++) {
            float4 a0 = *(const float4*)&As[k][ty * 8];
            float4 a1 = *(const float4*)&As[k][ty * 8 + 4];
            float4 b0 = *(const float4*)&Bs[k][tx * 8];
            float4 b1 = *(const float4*)&Bs[k][tx * 8 + 4];
            float am[8] = {a0.x, a0.y, a0.z, a0.w, a1.x, a1.y, a1.z, a1.w};
            float bn[8] = {b0.x, b0.y, b0.z, b0.w, b1.x, b1.y, b1.z, b1.w};
#pragma unroll
            for (int i = 0; i < 8; i++)
#pragma unroll
                for (int j = 0; j < 8; j++) acc[i][j] += am[i] * bn[j];
        }
        __syncthreads();
    }

#pragma unroll
    for (int i = 0; i < 8; i++) {
        int m = m0 + ty * 8 + i;
#pragma unroll
        for (int j = 0; j < 8; j++) {
            int n = n0 + tx * 8 + j;
            if (n < N) {
                size_t oi;
                if (TRANSOUT) oi = ((size_t)(m >> 6) * N + n) * 64 + (m & 63);
                else oi = (size_t)m * N + n;
                out[oi] = acc[i][j];
            }
        }
    }
}

// ---------------------------------------------------------------------------
// Persistent LSTM, 2 rows/block, unchanged.
// ---------------------------------------------------------------------------
__global__ __launch_bounds__(512, 2)
void lstm_kernel(const float* __restrict__ X, const float* __restrict__ Whh,
                 const float* __restrict__ hs_prev, const float* __restrict__ cs_prev,
                 const int* __restrict__ len1, const int* __restrict__ len2,
                 float* __restrict__ hs_out, float* __restrict__ cs_out)
{
    int t = threadIdx.x;
    int b0 = blockIdx.x * 2, b1 = b0 + 1;
    __shared__ float4 h0s4[25], h1s4[25];
    __shared__ float g0s[400], g1s[400];
    float* h0s = (float*)h0s4;
    float* h1s = (float*)h1s4;

    float4 w[25];
    if (t < 400) {
        const float* wr = Whh + t * 100;
#pragma unroll
        for (int i = 0; i < 25; i++) w[i] = ((const float4*)wr)[i];
    }
    float c0r = 0.f, c1r = 0.f;
    if (hs_prev) {
        if (t < 100) {
            int la = (b0 < 256) ? len1[b0] : len2[b0 - 256];
            h0s[t] = hs_prev[(b0 * 64 + la - 1) * 100 + t];
            c0r = cs_prev[(b0 * 64 + la - 1) * 100 + t];
        } else if (t < 200) {
            int j = t - 100;
            int la = (b1 < 256) ? len1[b1] : len2[b1 - 256];
            h1s[j] = hs_prev[(b1 * 64 + la - 1) * 100 + j];
            c1r = cs_prev[(b1 * 64 + la - 1) * 100 + j];
        }
    } else {
        if (t < 100) h0s[t] = 0.f;
        else if (t < 200) h1s[t - 100] = 0.f;
    }
    __syncthreads();

    for (int ts = 0; ts < 64; ts++) {
        if (t < 400) {
            float x0 = X[(ts * 512 + b0) * 400 + t];
            float x1 = X[(ts * 512 + b1) * 400 + t];
            float acc0a = 0.f, acc1a = 0.f;
            float acc0b = 0.f, acc1b = 0.f;
#pragma unroll
            for (int i = 0; i < 25; i++) {
                float4 hv0 = h0s4[i], hv1 = h1s4[i];
                acc0a += w[i].x * hv0.x + w[i].y * hv0.y;
                acc0b += w[i].z * hv0.z + w[i].w * hv0.w;
                acc1a += w[i].x * hv1.x + w[i].y * hv1.y;
                acc1b += w[i].z * hv1.z + w[i].w * hv1.w;
            }
            g0s[t] = acc0a + acc0b + x0;
            g1s[t] = acc1a + acc1b + x1;
        }
        __syncthreads();
        if (t < 200) {
            int j = (t < 100) ? t : t - 100;
            const float* gs = (t < 100) ? g0s : g1s;
            float ig = sigf(gs[j]);
            float fg = sigf(gs[100 + j]);
            float gg = tanhf(gs[200 + j]);
            float og = sigf(gs[300 + j]);
            float c = (t < 100) ? c0r : c1r;
            c = fg * c + ig * gg;
            float h = og * tanhf(c);
            if (t < 100) {
                c0r = c; h0s[j] = h;
                hs_out[(b0 * 64 + ts) * 100 + j] = h;
                if (cs_out) cs_out[(b0 * 64 + ts) * 100 + j] = c;
            } else {
                c1r = c; h1s[j] = h;
                hs_out[(b1 * 64 + ts) * 100 + j] = h;
                if (cs_out) cs_out[(b1 * 64 + ts) * 100 + j] = c;
            }
        }
        __syncthreads();
    }
}

// ---------------------------------------------------------------------------
// Balanced 4-wave attention: 512 blocks x 256 threads, one row per block.
// 3 barriers/step. Unnormalized-softmax: P5 stores ucv + den; P2 scales by
// rcp(den). outp columns live in registers (32/thread). Conflict-free LDS:
// wyy2[l][h] read pattern l*100+q*25+i hits all 32 banks 2-way (free).
// ---------------------------------------------------------------------------
__global__ __launch_bounds__(256, 2)
void attn_fast(const float* __restrict__ WyYT, const float* __restrict__ outp,
               const float* __restrict__ WhH, const float* __restrict__ Wr,
               const float* __restrict__ Wp, const float* __restrict__ aW,
               const float* __restrict__ mask1, const float* __restrict__ mask2,
               const int* __restrict__ len1, const int* __restrict__ len2,
               float* __restrict__ rep)
{
    int t = threadIdx.x;
    int bg = blockIdx.x;
    __shared__ __align__(16) float wyy2[64][100];  // 2*WyY, [l][h], 25.6 KB
    __shared__ float whq2[100];                    // 2*(wh + cv@Wr)
    __shared__ float atl[64];                      // unnormalized e_l
    __shared__ __align__(16) float ucv[104];       // unnormalized cv
    __shared__ float den[2];
    __shared__ float csel[100];

    int j = t >> 1, half = t & 1;      // P2/P5 roles (t<200)
    int l3 = t >> 2, q3 = t & 3;       // P3 roles (all 256)

    // stage 2*WyY transposed to [l][h]
    const float* wy = WyYT + (size_t)bg * 6400;     // [h][l]
    for (int idx = t; idx < 6400; idx += 256)
        wyy2[idx & 63][idx >> 6] = 2.f * wy[idx];

    // outp column halves -> registers (32 VGPR)
    const float* ob = outp + (size_t)bg * 6400;     // [l][h]
    float oreg[32];
    if (t < 200) {
#pragma unroll
        for (int i = 0; i < 32; i++)
            oreg[i] = ob[(half * 32 + i) * 100 + j];
    }
    // Wr half-columns -> registers (50 VGPR)
    float wrreg[50];
    if (t < 200) {
#pragma unroll
        for (int k = 0; k < 50; k++)
            wrreg[k] = Wr[(half * 50 + k) * 100 + j];
    }
    // 2*a quarter -> registers; sumA via q-shuffle
    float a2r[25];
#pragma unroll
    for (int i = 0; i < 25; i++) a2r[i] = 2.f * aW[q3 * 25 + i];
    float sumA;
    {
        float p = 0.f;
#pragma unroll
        for (int i = 0; i < 25; i++) p += a2r[i];
        p += __shfl_xor(p, 1);
        p += __shfl_xor(p, 2);
        sumA = 0.5f * p;
    }
    float m3 = (bg < 256) ? mask1[bg * 64 + l3] : mask2[(bg - 256) * 64 + l3];
    int lenB = (bg < 256) ? len2[bg] : len1[bg - 256];

    if (t < 104) ucv[t] = 0.f;
    if (t < 2) den[t] = 0.5f;          // den0+den1 = 1 -> rd=1, dot=0 at ts=0

    const float* whrow = WhH + (size_t)bg * 6400;
    float whc = (t < 200) ? whrow[j] : 0.f;
    float densel = 1.f, uselreg = 0.f;
    __syncthreads();

    for (int ts = 0; ts < 64; ts++) {
        // ---- P2: whq2[j] = 2*(wh + (wr . ucv) * rcp(den)) ----
        if (t < 200) {
            float dsum = den[0] + den[1];
            if (ts == lenB) densel = dsum;               // den of step lenB-1
            float rd = __builtin_amdgcn_rcpf(dsum);
            float whn = (ts < 63) ? whrow[(ts + 1) * 100 + j] : 0.f;
            float p0 = 0.f, p1 = 0.f;
            const float2* uc2 = (const float2*)(ucv + half * 50);
#pragma unroll
            for (int i = 0; i < 25; i++) {
                float2 c = uc2[i];
                p0 += wrreg[2 * i] * c.x;
                p1 += wrreg[2 * i + 1] * c.y;
            }
            float comb = p0 + p1;
            comb += __shfl_xor(comb, 1);
            if (!half) whq2[j] = 2.f * (whc + comb * rd);
            whc = whn;
        }
        __syncthreads();
        // ---- P3: e_l = exp(sumA - sum_h 2a/(exp(2x)+1)) * m_l ----
        {
            const float* wyr = &wyy2[l3][q3 * 25];
            const float* wqp = &whq2[q3 * 25];
            float neg = 0.f;
#pragma unroll
            for (int i = 0; i < 25; i++) {
                float arg = wyr[i] + m3 * wqp[i];
                neg += a2r[i] * __builtin_amdgcn_rcpf(__expf(arg) + 1.f);
            }
            neg += __shfl_xor(neg, 1);
            neg += __shfl_xor(neg, 2);
            float e = __expf(sumA - neg) * m3;
            if (q3 == 0) atl[l3] = e;
        }
        __syncthreads();
        // ---- P5: ucv[j] = sum_l e_l * outp[l][j]; den = sum_l e_l ----
        if (t < 200) {
            const float* al = &atl[half * 32];
            float p0 = 0.f, p1 = 0.f;
#pragma unroll
            for (int i = 0; i < 16; i++) {
                p0 += al[2 * i] * oreg[2 * i];
                p1 += al[2 * i + 1] * oreg[2 * i + 1];
            }
            float comb = p0 + p1;
            comb += __shfl_xor(comb, 1);
            if (ts == lenB - 1) uselreg = comb;
            if (!half) ucv[j] = comb;
        } else if (t < 202) {
            int hh = t - 200;
            const float* al = &atl[hh * 32];
            float d = 0.f;
#pragma unroll
            for (int i = 0; i < 32; i++) d += al[i];
            den[hh] = d;
        }
        __syncthreads();
    }

    // epilogue: rep = tanh(cv_sel @ Wp + WhH[lenB-1])
    if (lenB == 64 && t < 200) densel = den[0] + den[1];
    if (t < 200 && !half) csel[j] = uselreg * __builtin_amdgcn_rcpf(densel);
    __syncthreads();
    if (t < 100) {
        float r = whrow[(lenB - 1) * 100 + t];
#pragma unroll
        for (int k = 0; k < 100; k++) r += csel[k] * Wp[k * 100 + t];
        rep[(size_t)bg * 100 + t] = tanhf(r);
    }
}

// ---------------------------------------------------------------------------
// Classifier, unchanged.
// ---------------------------------------------------------------------------
__global__ void final_kernel(const float* __restrict__ rep,
                             const float* __restrict__ W1, const float* __restrict__ b1,
                             const float* __restrict__ W2, const float* __restrict__ b2,
                             float* __restrict__ out)
{
    int b = blockIdx.x;
    int t = threadIdx.x;
    __shared__ float4 fin4[50];
    __shared__ float4 fc4[50];
    __shared__ float lg[3];
    float* fin = (float*)fin4;
    float* fc = (float*)fc4;
    if (t < 200) fin[t] = (t < 100) ? rep[b * 100 + t] : rep[(b + 256) * 100 + (t - 100)];
    __syncthreads();
    if (t < 200) {
        float acc = b1[t];
        const float4* w = (const float4*)(W1 + t * 200);
#pragma unroll
        for (int k = 0; k < 50; k++) {
            float4 wv = w[k];
            float4 fv = fin4[k];
            acc += wv.x * fv.x + wv.y * fv.y + wv.z * fv.z + wv.w * fv.w;
        }
        fc[t] = tanhf(acc);
    }
    __syncthreads();
    if (t < 3) {
        float acc = b2[t];
        const float4* w = (const float4*)(W2 + t * 200);
        for (int k = 0; k < 50; k++) {
            float4 wv = w[k];
            float4 fv = fc4[k];
            acc += wv.x * fv.x + wv.y * fv.y + wv.z * fv.z + wv.w * fv.w;
        }
        lg[t] = acc;
    }
    __syncthreads();
    if (t == 0) {
        float m = fmaxf(lg[0], fmaxf(lg[1], lg[2]));
        float s = expf(lg[0] - m) + expf(lg[1] - m) + expf(lg[2] - m);
        float lse = m + logf(s);
        out[b * 3 + 0] = lg[0] - lse;
        out[b * 3 + 1] = lg[1] - lse;
        out[b * 3 + 2] = lg[2] - lse;
    }
}

// ---------------------------------------------------------------------------
extern "C" void kernel_launch(void* const* d_in, const int* in_sizes, int n_in,
                              void* d_out, int out_size, void* d_ws, size_t ws_size,
                              hipStream_t stream)
{
    const int*   rep1  = (const int*)d_in[0];
    const int*   len1  = (const int*)d_in[1];
    const float* mask1 = (const float*)d_in[2];
    const int*   rep2  = (const int*)d_in[3];
    const int*   len2  = (const int*)d_in[4];
    const float* mask2 = (const float*)d_in[5];
    const float* emb   = (const float*)d_in[6];
    const float* W_ih1 = (const float*)d_in[7];
    const float* W_hh1 = (const float*)d_in[8];
    const float* b_ih1 = (const float*)d_in[9];
    const float* b_hh1 = (const float*)d_in[10];
    const float* W_ih2 = (const float*)d_in[11];
    const float* W_hh2 = (const float*)d_in[12];
    const float* b_ih2 = (const float*)d_in[13];
    const float* b_hh2 = (const float*)d_in[14];
    const float* Wy    = (const float*)d_in[15];
    const float* Wh    = (const float*)d_in[16];
    const float* Wr    = (const float*)d_in[17];
    const float* Wp    = (const float*)d_in[18];
    const float* aW    = (const float*)d_in[19];
    const float* W1    = (const float*)d_in[20];
    const float* b1    = (const float*)d_in[21];
    const float* W2    = (const float*)d_in[22];
    const float* b2    = (const float*)d_in[23];

    float* ws = (float*)d_ws;
    float* X    = ws;                    // 64*512*400 = 13,107,200 (reused as WhH_pre)
    float* hs1  = X + 13107200;          // 512*64*100
    float* cs1  = hs1 + 3276800;
    float* hs2  = cs1 + 3276800;
    float* WyYT = hs2 + 3276800;
    float* rep  = WyYT + 3276800;        // 512*100
    // emb_bf16 overlay on hs2 (+WyYT head); dead before lstm2/WyYT-gemm write.
    unsigned short* embb = (unsigned short*)hs2;

    dim3 gm(256, 5);   // MFMA gather-GEMM: M/128=256, N/80=5
    dim3 gw(256, 1);   // fp32 GEMM N=100

    // 1. emb -> bf16
    f32_to_bf16_kernel<<<1024, 256, 0, stream>>>(emb, embb, 2250000);
    // 2. Xa = gather(emb_bf) @ W_ih1^T + b_ih1 + b_hh1   (MFMA)
    gemm_xproj_mfma<<<gm, 256, 0, stream>>>(embb, rep1, rep2, W_ih1, b_ih1, b_hh1, X);
    // 3. LSTM1 (zero init) -> hs1, cs1
    lstm_kernel<<<256, 512, 0, stream>>>(X, W_hh1, nullptr, nullptr, nullptr, nullptr, hs1, cs1);
    // 4. Xb = gather(emb_bf, swapped) @ W_ih2^T + biases  (MFMA, reuse X; embb last use)
    gemm_xproj_mfma<<<gm, 256, 0, stream>>>(embb, rep2, rep1, W_ih2, b_ih2, b_hh2, X);
    // 5. WyYT = (hs1 @ Wy) transposed per row [512][100][64]
    gemm_kernel<1, 1><<<gw, 256, 0, stream>>>(hs1, Wy, WyYT, 32768, 100, 100, 100);
    // 6. LSTM2 -> hs2
    lstm_kernel<<<256, 512, 0, stream>>>(X, W_hh2, hs1, cs1, len1, len2, hs2, nullptr);
    // 7. WhH_pre = hs2 @ Wh -> X
    gemm_kernel<1, 0><<<gw, 256, 0, stream>>>(hs2, Wh, X, 32768, 100, 100, 100);
    // 8. attention scan -> rep
    attn_fast<<<512, 256, 0, stream>>>(WyYT, hs1, X, Wr, Wp, aW,
                                       mask1, mask2, len1, len2, rep);
    // 9. classifier
    final_kernel<<<256, 256, 0, stream>>>(rep, W1, b1, W2, b2, (float*)d_out);
}

// Round 10
// 678.546 us; speedup vs baseline: 4.2530x; 1.0579x over previous
//
#include <hip/hip_runtime.h>
#include <math.h>

// Problem dims: B=256, L=64, E=300, H=100, HID=200, V=30000, C=3
// Combined batch CB=512 (dir1 rows 0..255, dir2 rows 256..511)

__device__ __forceinline__ float sigf(float x) { return 1.f / (1.f + expf(-x)); }
__device__ __forceinline__ float fsig(float x) { return __builtin_amdgcn_rcpf(1.f + __expf(-x)); }
__device__ __forceinline__ float ftanh(float x) { return 1.f - 2.f * __builtin_amdgcn_rcpf(__expf(2.f * x) + 1.f); }

__device__ __forceinline__ unsigned short f2b(float f) {
    unsigned int u = __float_as_uint(f);
    unsigned int r = (u + 0x7FFFu + ((u >> 16) & 1u)) >> 16;   // RNE
    return (unsigned short)r;
}

typedef __attribute__((ext_vector_type(8))) short short8v;
typedef __attribute__((ext_vector_type(4))) float float4v;

// ---------------------------------------------------------------------------
// fp32 -> bf16 bulk convert (for emb); n4 = count/4
// ---------------------------------------------------------------------------
__global__ void f32_to_bf16_kernel(const float* __restrict__ in,
                                   unsigned short* __restrict__ out, int n4)
{
    int i = blockIdx.x * blockDim.x + threadIdx.x;
    int stride = gridDim.x * blockDim.x;
    for (; i < n4; i += stride) {
        float4 v = ((const float4*)in)[i];
        ushort4 b;
        b.x = f2b(v.x); b.y = f2b(v.y); b.z = f2b(v.z); b.w = f2b(v.w);
        ((ushort4*)out)[i] = b;
    }
}

// ---------------------------------------------------------------------------
// MFMA bf16 gather-GEMM (unchanged; passed absmax 7.8e-3).
// ---------------------------------------------------------------------------
__global__ __launch_bounds__(256)
void gemm_xproj_mfma(const unsigned short* __restrict__ embb,
                     const int* __restrict__ repA, const int* __restrict__ repB,
                     const float* __restrict__ W,
                     const float* __restrict__ bias1, const float* __restrict__ bias2,
                     float* __restrict__ out)
{
    __shared__ __align__(16) unsigned short Afr[512 * 8];  // 8 KB
    __shared__ __align__(16) unsigned short Bfr[320 * 8];  // 5 KB
    int tid = threadIdx.x;
    int m0 = blockIdx.x * 128;
    int n0 = blockIdx.y * 80;
    int lane = tid & 63, wave = tid >> 6;

    int sA0 = tid * 2, sA1 = sA0 + 1;
    int lA0 = sA0 & 63, lA1 = sA1 & 63;
    int rA0 = m0 + (sA0 >> 6) * 16 + (lA0 & 15);
    int rA1 = m0 + (sA1 >> 6) * 16 + (lA1 & 15);
    int kgA0 = (lA0 >> 4) * 8, kgA1 = (lA1 >> 4) * 8;
    int tt0 = rA0 >> 9, bb0 = rA0 & 511;
    int tok0 = (bb0 < 256) ? repA[bb0 * 64 + tt0] : repB[(bb0 - 256) * 64 + tt0];
    int tt1 = rA1 >> 9, bb1 = rA1 & 511;
    int tok1 = (bb1 < 256) ? repA[bb1 * 64 + tt1] : repB[(bb1 - 256) * 64 + tt1];
    const unsigned short* pa0 = embb + (size_t)tok0 * 300 + kgA0;
    const unsigned short* pa1 = embb + (size_t)tok1 * 300 + kgA1;

    int sB0 = tid;
    int nB0 = n0 + (sB0 >> 6) * 16 + (sB0 & 15);
    int kgB0 = ((sB0 & 63) >> 4) * 8;
    const float* pb0 = W + (size_t)nB0 * 300 + kgB0;
    int nB1 = n0 + 64 + (tid & 15);
    int kgB1 = (tid >> 4) * 8;
    const float* pb1 = W + (size_t)nB1 * 300 + kgB1;

    float4v acc[2][5];
#pragma unroll
    for (int i = 0; i < 2; i++)
#pragma unroll
        for (int j = 0; j < 5; j++) acc[i][j] = (float4v){0.f, 0.f, 0.f, 0.f};

    for (int k0 = 0; k0 < 300; k0 += 32) {
        {
            unsigned short* d = &Afr[sA0 * 8];
            int kk = k0 + kgA0;
            if (kk + 8 <= 300) {
                *(ushort4*)d = *(const ushort4*)(pa0 + k0);
                *(ushort4*)(d + 4) = *(const ushort4*)(pa0 + k0 + 4);
            } else {
#pragma unroll
                for (int i = 0; i < 8; i++) d[i] = (kk + i < 300) ? pa0[k0 + i] : 0;
            }
        }
        {
            unsigned short* d = &Afr[sA1 * 8];
            int kk = k0 + kgA1;
            if (kk + 8 <= 300) {
                *(ushort4*)d = *(const ushort4*)(pa1 + k0);
                *(ushort4*)(d + 4) = *(const ushort4*)(pa1 + k0 + 4);
            } else {
#pragma unroll
                for (int i = 0; i < 8; i++) d[i] = (kk + i < 300) ? pa1[k0 + i] : 0;
            }
        }
        {
            unsigned short* d = &Bfr[sB0 * 8];
            int kk = k0 + kgB0;
            if (kk + 8 <= 300) {
                float4 lo = *(const float4*)(pb0 + k0);
                float4 hi = *(const float4*)(pb0 + k0 + 4);
                d[0] = f2b(lo.x); d[1] = f2b(lo.y); d[2] = f2b(lo.z); d[3] = f2b(lo.w);
                d[4] = f2b(hi.x); d[5] = f2b(hi.y); d[6] = f2b(hi.z); d[7] = f2b(hi.w);
            } else {
#pragma unroll
                for (int i = 0; i < 8; i++) d[i] = (kk + i < 300) ? f2b(pb0[k0 + i]) : 0;
            }
        }
        if (tid < 64) {
            unsigned short* d = &Bfr[(256 + tid) * 8];
            int kk = k0 + kgB1;
            if (kk + 8 <= 300) {
                float4 lo = *(const float4*)(pb1 + k0);
                float4 hi = *(const float4*)(pb1 + k0 + 4);
                d[0] = f2b(lo.x); d[1] = f2b(lo.y); d[2] = f2b(lo.z); d[3] = f2b(lo.w);
                d[4] = f2b(hi.x); d[5] = f2b(hi.y); d[6] = f2b(hi.z); d[7] = f2b(hi.w);
            } else {
#pragma unroll
                for (int i = 0; i < 8; i++) d[i] = (kk + i < 300) ? f2b(pb1[k0 + i]) : 0;
            }
        }
        __syncthreads();
        short8v a0 = ((const short8v*)Afr)[(wave * 2 + 0) * 64 + lane];
        short8v a1 = ((const short8v*)Afr)[(wave * 2 + 1) * 64 + lane];
#pragma unroll
        for (int nt = 0; nt < 5; nt++) {
            short8v b = ((const short8v*)Bfr)[nt * 64 + lane];
            acc[0][nt] = __builtin_amdgcn_mfma_f32_16x16x32_bf16(a0, b, acc[0][nt], 0, 0, 0);
            acc[1][nt] = __builtin_amdgcn_mfma_f32_16x16x32_bf16(a1, b, acc[1][nt], 0, 0, 0);
        }
        __syncthreads();
    }

    int rbase = (lane >> 4) * 4;
    int cbase = lane & 15;
#pragma unroll
    for (int mtl = 0; mtl < 2; mtl++) {
        int mt = wave * 2 + mtl;
#pragma unroll
        for (int nt = 0; nt < 5; nt++) {
            int col = n0 + nt * 16 + cbase;
            float bsum = bias1[col] + bias2[col];
#pragma unroll
            for (int r = 0; r < 4; r++) {
                int row = m0 + mt * 16 + rbase + r;
                out[(size_t)row * 400 + col] = acc[mtl][nt][r] + bsum;
            }
        }
    }
}

// ---------------------------------------------------------------------------
// fp32 GEMM (WyYT / WhH_pre): out = A * B (KxN), optional TRANSOUT
// ---------------------------------------------------------------------------
template<int TRANSB, int TRANSOUT>
__global__ void gemm_kernel(const float* __restrict__ A,
                            const float* __restrict__ Bm,
                            float* __restrict__ out, int M, int N, int K, int lda)
{
    __shared__ float As[8][132];
    __shared__ float Bs[8][132];
    int tid = threadIdx.x;
    int m0 = blockIdx.x * 128;
    int n0 = blockIdx.y * 128;
    int tx = tid & 15, ty = tid >> 4;
    float acc[8][8];
#pragma unroll
    for (int i = 0; i < 8; i++)
#pragma unroll
        for (int j = 0; j < 8; j++) acc[i][j] = 0.f;

    int mr = m0 + (tid >> 1);
    int p = tid & 1;
    const float* arow = A + (size_t)mr * lda;

    for (int k0 = 0; k0 < K; k0 += 8) {
        int kk = k0 + p * 4;
        float4 av = make_float4(0.f, 0.f, 0.f, 0.f);
        if (kk + 3 < K) {
            av = *(const float4*)(arow + kk);
        } else {
            float tmp[4] = {0.f, 0.f, 0.f, 0.f};
            for (int i = 0; i < 4; i++) if (kk + i < K) tmp[i] = arow[kk + i];
            av = make_float4(tmp[0], tmp[1], tmp[2], tmp[3]);
        }
        int ml = tid >> 1;
        As[p * 4 + 0][ml] = av.x; As[p * 4 + 1][ml] = av.y;
        As[p * 4 + 2][ml] = av.z; As[p * 4 + 3][ml] = av.w;

        {
            int kl = tid >> 5;
            int nc = (tid & 31) * 4;
            int krow = k0 + kl;
            float4 bv = make_float4(0.f, 0.f, 0.f, 0.f);
            if (krow < K) {
                if (n0 + nc + 3 < N) {
                    bv = *(const float4*)(Bm + (size_t)krow * N + n0 + nc);
                } else {
                    float tmp[4] = {0.f, 0.f, 0.f, 0.f};
                    for (int i = 0; i < 4; i++) if (n0 + nc + i < N) tmp[i] = Bm[(size_t)krow * N + n0 + nc + i];
                    bv = make_float4(tmp[0], tmp[1], tmp[2], tmp[3]);
                }
            }
            Bs[kl][nc + 0] = bv.x; Bs[kl][nc + 1] = bv.y;
            Bs[kl][nc + 2] = bv.z; Bs[kl][nc + 3] = bv.w;
        }
        __syncthreads();
#pragma unroll
        for (int k = 0; k < 8; k++) {
            float4 a0 = *(const float4*)&As[k][ty * 8];
            float4 a1 = *(const float4*)&As[k][ty * 8 + 4];
            float4 b0 = *(const float4*)&Bs[k][tx * 8];
            float4 b1 = *(const float4*)&Bs[k][tx * 8 + 4];
            float am[8] = {a0.x, a0.y, a0.z, a0.w, a1.x, a1.y, a1.z, a1.w};
            float bn[8] = {b0.x, b0.y, b0.z, b0.w, b1.x, b1.y, b1.z, b1.w};
#pragma unroll
            for (int i = 0; i < 8; i++)
#pragma unroll
                for (int j = 0; j < 8; j++) acc[i][j] += am[i] * bn[j];
        }
        __syncthreads();
    }

#pragma unroll
    for (int i = 0; i < 8; i++) {
        int m = m0 + ty * 8 + i;
#pragma unroll
        for (int j = 0; j < 8; j++) {
            int n = n0 + tx * 8 + j;
            if (n < N) {
                size_t oi;
                if (TRANSOUT) oi = ((size_t)(m >> 6) * N + n) * 64 + (m & 63);
                else oi = (size_t)m * N + n;
                out[oi] = acc[i][j];
            }
        }
    }
}

// ---------------------------------------------------------------------------
// Wave-synchronous LSTM: one block = one combined-batch row, 512 blocks x 512.
// Lane layout: wave w, lane l -> element e = w*16+(l&15), gate q = l>>4
// (i,f,g,o = Whh rows q*100+e). Each lane: 1 gate dot (100 VGPR weights,
// broadcast LDS h reads). Gates exchanged via 4 intra-wave shuffles.
// h double-buffered in LDS -> ONE barrier per step. X prefetched 1 step ahead.
// Fast transcendentals (__expf + rcp).
// ---------------------------------------------------------------------------
__global__ __launch_bounds__(512)
void lstm_wave(const float* __restrict__ X, const float* __restrict__ Whh,
               const float* __restrict__ hs_prev, const float* __restrict__ cs_prev,
               const int* __restrict__ len1, const int* __restrict__ len2,
               float* __restrict__ hs_out, float* __restrict__ cs_out)
{
    int t = threadIdx.x;
    int bg = blockIdx.x;
    int lane = t & 63;
    int wave = t >> 6;
    int sub = lane & 15;
    int q = lane >> 4;                 // 0..3 = i,f,g,o
    int e = wave * 16 + sub;           // 0..127 (100 valid)
    bool act = e < 100;
    int ew = act ? e : 0;

    __shared__ __align__(16) float hbuf[2][104];

    // Whh row for (gate q, element e) in registers: 25 float4 = 100 VGPR
    float4 w[25];
    {
        const float4* wr = (const float4*)(Whh + (size_t)(q * 100 + ew) * 100);
#pragma unroll
        for (int i = 0; i < 25; i++) w[i] = wr[i];
    }

    float c = 0.f;
    if (hs_prev) {
        int la = (bg < 256) ? len1[bg] : len2[bg - 256];
        size_t off = ((size_t)bg * 64 + la - 1) * 100 + ew;
        c = cs_prev[off];
        if (act && q == 0) hbuf[0][e] = hs_prev[off];
    } else {
        if (act && q == 0) hbuf[0][e] = 0.f;
    }

    const float* xp = X + (size_t)bg * 400 + (q * 100 + ew);  // + ts*204800
    float xv = xp[0];
    float* hs_row = hs_out + (size_t)bg * 6400;
    float* cs_row = cs_out ? (cs_out + (size_t)bg * 6400) : nullptr;
    __syncthreads();

    for (int ts = 0; ts < 64; ts++) {
        float xn = 0.f;
        if (ts < 63) xn = xp[(size_t)(ts + 1) * 204800];
        // gate dot: 25 float4 broadcast reads, 4 accumulator chains
        const float4* h4 = (const float4*)hbuf[ts & 1];
        float a0 = 0.f, a1 = 0.f, a2 = 0.f, a3 = 0.f;
#pragma unroll
        for (int i = 0; i < 24; i += 4) {
            float4 h0 = h4[i], h1 = h4[i + 1], h2 = h4[i + 2], h3 = h4[i + 3];
            a0 += w[i].x * h0.x + w[i].y * h0.y + w[i].z * h0.z + w[i].w * h0.w;
            a1 += w[i+1].x * h1.x + w[i+1].y * h1.y + w[i+1].z * h1.z + w[i+1].w * h1.w;
            a2 += w[i+2].x * h2.x + w[i+2].y * h2.y + w[i+2].z * h2.z + w[i+2].w * h2.w;
            a3 += w[i+3].x * h3.x + w[i+3].y * h3.y + w[i+3].z * h3.z + w[i+3].w * h3.w;
        }
        {
            float4 h0 = h4[24];
            a0 += w[24].x * h0.x + w[24].y * h0.y + w[24].z * h0.z + w[24].w * h0.w;
        }
        float gv = (a0 + a1) + (a2 + a3) + xv;
        // exchange gates within wave: lanes {sub, sub+16, sub+32, sub+48}
        float gi = __shfl(gv, sub);
        float gf = __shfl(gv, sub + 16);
        float gg = __shfl(gv, sub + 32);
        float go = __shfl(gv, sub + 48);
        c = fsig(gf) * c + fsig(gi) * ftanh(gg);
        float h = fsig(go) * ftanh(c);
        if (act && q == 0) {
            hbuf[(ts + 1) & 1][e] = h;
            hs_row[ts * 100 + e] = h;
            if (cs_row) cs_row[ts * 100 + e] = c;
        }
        __syncthreads();
        xv = xn;
    }
}

// ---------------------------------------------------------------------------
// Balanced 4-wave attention (unchanged from round 9).
// ---------------------------------------------------------------------------
__global__ __launch_bounds__(256, 2)
void attn_fast(const float* __restrict__ WyYT, const float* __restrict__ outp,
               const float* __restrict__ WhH, const float* __restrict__ Wr,
               const float* __restrict__ Wp, const float* __restrict__ aW,
               const float* __restrict__ mask1, const float* __restrict__ mask2,
               const int* __restrict__ len1, const int* __restrict__ len2,
               float* __restrict__ rep)
{
    int t = threadIdx.x;
    int bg = blockIdx.x;
    __shared__ __align__(16) float wyy2[64][100];
    __shared__ float whq2[100];
    __shared__ float atl[64];
    __shared__ __align__(16) float ucv[104];
    __shared__ float den[2];
    __shared__ float csel[100];

    int j = t >> 1, half = t & 1;
    int l3 = t >> 2, q3 = t & 3;

    const float* wy = WyYT + (size_t)bg * 6400;
    for (int idx = t; idx < 6400; idx += 256)
        wyy2[idx & 63][idx >> 6] = 2.f * wy[idx];

    const float* ob = outp + (size_t)bg * 6400;
    float oreg[32];
    if (t < 200) {
#pragma unroll
        for (int i = 0; i < 32; i++)
            oreg[i] = ob[(half * 32 + i) * 100 + j];
    }
    float wrreg[50];
    if (t < 200) {
#pragma unroll
        for (int k = 0; k < 50; k++)
            wrreg[k] = Wr[(half * 50 + k) * 100 + j];
    }
    float a2r[25];
#pragma unroll
    for (int i = 0; i < 25; i++) a2r[i] = 2.f * aW[q3 * 25 + i];
    float sumA;
    {
        float p = 0.f;
#pragma unroll
        for (int i = 0; i < 25; i++) p += a2r[i];
        p += __shfl_xor(p, 1);
        p += __shfl_xor(p, 2);
        sumA = 0.5f * p;
    }
    float m3 = (bg < 256) ? mask1[bg * 64 + l3] : mask2[(bg - 256) * 64 + l3];
    int lenB = (bg < 256) ? len2[bg] : len1[bg - 256];

    if (t < 104) ucv[t] = 0.f;
    if (t < 2) den[t] = 0.5f;

    const float* whrow = WhH + (size_t)bg * 6400;
    float whc = (t < 200) ? whrow[j] : 0.f;
    float densel = 1.f, uselreg = 0.f;
    __syncthreads();

    for (int ts = 0; ts < 64; ts++) {
        if (t < 200) {
            float dsum = den[0] + den[1];
            if (ts == lenB) densel = dsum;
            float rd = __builtin_amdgcn_rcpf(dsum);
            float whn = (ts < 63) ? whrow[(ts + 1) * 100 + j] : 0.f;
            float p0 = 0.f, p1 = 0.f;
            const float2* uc2 = (const float2*)(ucv + half * 50);
#pragma unroll
            for (int i = 0; i < 25; i++) {
                float2 cc = uc2[i];
                p0 += wrreg[2 * i] * cc.x;
                p1 += wrreg[2 * i + 1] * cc.y;
            }
            float comb = p0 + p1;
            comb += __shfl_xor(comb, 1);
            if (!half) whq2[j] = 2.f * (whc + comb * rd);
            whc = whn;
        }
        __syncthreads();
        {
            const float* wyr = &wyy2[l3][q3 * 25];
            const float* wqp = &whq2[q3 * 25];
            float neg = 0.f;
#pragma unroll
            for (int i = 0; i < 25; i++) {
                float arg = wyr[i] + m3 * wqp[i];
                neg += a2r[i] * __builtin_amdgcn_rcpf(__expf(arg) + 1.f);
            }
            neg += __shfl_xor(neg, 1);
            neg += __shfl_xor(neg, 2);
            float e = __expf(sumA - neg) * m3;
            if (q3 == 0) atl[l3] = e;
        }
        __syncthreads();
        if (t < 200) {
            const float* al = &atl[half * 32];
            float p0 = 0.f, p1 = 0.f;
#pragma unroll
            for (int i = 0; i < 16; i++) {
                p0 += al[2 * i] * oreg[2 * i];
                p1 += al[2 * i + 1] * oreg[2 * i + 1];
            }
            float comb = p0 + p1;
            comb += __shfl_xor(comb, 1);
            if (ts == lenB - 1) uselreg = comb;
            if (!half) ucv[j] = comb;
        } else if (t < 202) {
            int hh = t - 200;
            const float* al = &atl[hh * 32];
            float d = 0.f;
#pragma unroll
            for (int i = 0; i < 32; i++) d += al[i];
            den[hh] = d;
        }
        __syncthreads();
    }

    if (lenB == 64 && t < 200) densel = den[0] + den[1];
    if (t < 200 && !half) csel[j] = uselreg * __builtin_amdgcn_rcpf(densel);
    __syncthreads();
    if (t < 100) {
        float r = whrow[(lenB - 1) * 100 + t];
#pragma unroll
        for (int k = 0; k < 100; k++) r += csel[k] * Wp[k * 100 + t];
        rep[(size_t)bg * 100 + t] = tanhf(r);
    }
}

// ---------------------------------------------------------------------------
// Classifier, unchanged.
// ---------------------------------------------------------------------------
__global__ void final_kernel(const float* __restrict__ rep,
                             const float* __restrict__ W1, const float* __restrict__ b1,
                             const float* __restrict__ W2, const float* __restrict__ b2,
                             float* __restrict__ out)
{
    int b = blockIdx.x;
    int t = threadIdx.x;
    __shared__ float4 fin4[50];
    __shared__ float4 fc4[50];
    __shared__ float lg[3];
    float* fin = (float*)fin4;
    float* fc = (float*)fc4;
    if (t < 200) fin[t] = (t < 100) ? rep[b * 100 + t] : rep[(b + 256) * 100 + (t - 100)];
    __syncthreads();
    if (t < 200) {
        float acc = b1[t];
        const float4* w = (const float4*)(W1 + t * 200);
#pragma unroll
        for (int k = 0; k < 50; k++) {
            float4 wv = w[k];
            float4 fv = fin4[k];
            acc += wv.x * fv.x + wv.y * fv.y + wv.z * fv.z + wv.w * fv.w;
        }
        fc[t] = tanhf(acc);
    }
    __syncthreads();
    if (t < 3) {
        float acc = b2[t];
        const float4* w = (const float4*)(W2 + t * 200);
        for (int k = 0; k < 50; k++) {
            float4 wv = w[k];
            float4 fv = fc4[k];
            acc += wv.x * fv.x + wv.y * fv.y + wv.z * fv.z + wv.w * fv.w;
        }
        lg[t] = acc;
    }
    __syncthreads();
    if (t == 0) {
        float m = fmaxf(lg[0], fmaxf(lg[1], lg[2]));
        float s = expf(lg[0] - m) + expf(lg[1] - m) + expf(lg[2] - m);
        float lse = m + logf(s);
        out[b * 3 + 0] = lg[0] - lse;
        out[b * 3 + 1] = lg[1] - lse;
        out[b * 3 + 2] = lg[2] - lse;
    }
}

// ---------------------------------------------------------------------------
extern "C" void kernel_launch(void* const* d_in, const int* in_sizes, int n_in,
                              void* d_out, int out_size, void* d_ws, size_t ws_size,
                              hipStream_t stream)
{
    const int*   rep1  = (const int*)d_in[0];
    const int*   len1  = (const int*)d_in[1];
    const float* mask1 = (const float*)d_in[2];
    const int*   rep2  = (const int*)d_in[3];
    const int*   len2  = (const int*)d_in[4];
    const float* mask2 = (const float*)d_in[5];
    const float* emb   = (const float*)d_in[6];
    const float* W_ih1 = (const float*)d_in[7];
    const float* W_hh1 = (const float*)d_in[8];
    const float* b_ih1 = (const float*)d_in[9];
    const float* b_hh1 = (const float*)d_in[10];
    const float* W_ih2 = (const float*)d_in[11];
    const float* W_hh2 = (const float*)d_in[12];
    const float* b_ih2 = (const float*)d_in[13];
    const float* b_hh2 = (const float*)d_in[14];
    const float* Wy    = (const float*)d_in[15];
    const float* Wh    = (const float*)d_in[16];
    const float* Wr    = (const float*)d_in[17];
    const float* Wp    = (const float*)d_in[18];
    const float* aW    = (const float*)d_in[19];
    const float* W1    = (const float*)d_in[20];
    const float* b1    = (const float*)d_in[21];
    const float* W2    = (const float*)d_in[22];
    const float* b2    = (const float*)d_in[23];

    float* ws = (float*)d_ws;
    float* X    = ws;                    // 64*512*400 = 13,107,200 (reused as WhH_pre)
    float* hs1  = X + 13107200;          // 512*64*100
    float* cs1  = hs1 + 3276800;
    float* hs2  = cs1 + 3276800;
    float* WyYT = hs2 + 3276800;
    float* rep  = WyYT + 3276800;        // 512*100
    // emb_bf16 overlay on hs2 (+WyYT head); dead before lstm2/WyYT-gemm write.
    unsigned short* embb = (unsigned short*)hs2;

    dim3 gm(256, 5);   // MFMA gather-GEMM: M/128=256, N/80=5
    dim3 gw(256, 1);   // fp32 GEMM N=100

    // 1. emb -> bf16
    f32_to_bf16_kernel<<<1024, 256, 0, stream>>>(emb, embb, 2250000);
    // 2. Xa = gather(emb_bf) @ W_ih1^T + b_ih1 + b_hh1   (MFMA)
    gemm_xproj_mfma<<<gm, 256, 0, stream>>>(embb, rep1, rep2, W_ih1, b_ih1, b_hh1, X);
    // 3. LSTM1 (zero init) -> hs1, cs1
    lstm_wave<<<512, 512, 0, stream>>>(X, W_hh1, nullptr, nullptr, nullptr, nullptr, hs1, cs1);
    // 4. Xb = gather(emb_bf, swapped) @ W_ih2^T + biases  (MFMA, reuse X; embb last use)
    gemm_xproj_mfma<<<gm, 256, 0, stream>>>(embb, rep2, rep1, W_ih2, b_ih2, b_hh2, X);
    // 5. WyYT = (hs1 @ Wy) transposed per row [512][100][64]
    gemm_kernel<1, 1><<<gw, 256, 0, stream>>>(hs1, Wy, WyYT, 32768, 100, 100, 100);
    // 6. LSTM2 -> hs2
    lstm_wave<<<512, 512, 0, stream>>>(X, W_hh2, hs1, cs1, len1, len2, hs2, nullptr);
    // 7. WhH_pre = hs2 @ Wh -> X
    gemm_kernel<1, 0><<<gw, 256, 0, stream>>>(hs2, Wh, X, 32768, 100, 100, 100);
    // 8. attention scan -> rep
    attn_fast<<<512, 256, 0, stream>>>(WyYT, hs1, X, Wr, Wp, aW,
                                       mask1, mask2, len1, len2, rep);
    // 9. classifier
    final_kernel<<<256, 256, 0, stream>>>(rep, W1, b1, W2, b2, (float*)d_out);
}